// Round 3
// baseline (284.538 us; speedup 1.0000x reference)
//
#include <hip/hip_runtime.h>
#include <math.h>

#define DIN 1024
#define DH 512
#define DATT 256
#define CNUM 10
#define NCLS 4
#define NH 64              // histogram blocks (fallback path)
#define NSC 40             // scatter blocks

typedef __attribute__((ext_vector_type(8))) short bf16x8;
typedef __attribute__((ext_vector_type(4))) float f32x4;
typedef unsigned short ushort_t;
typedef unsigned int uint_t;

__device__ inline ushort_t f2bf(float f) {
    uint_t u = __float_as_uint(f);
    u += 0x7FFF + ((u >> 16) & 1);   // RNE
    return (ushort_t)(u >> 16);
}

// packed f32x2 -> bf16x2 (RNE), single VALU op
__device__ inline uint_t pkbf(float lo, float hi) {
    uint_t r;
    asm("v_cvt_pk_bf16_f32 %0, %1, %2" : "=v"(r) : "v"(lo), "v"(hi));
    return r;
}

// async global->LDS, 16B per lane. LDS dst must be wave-uniform base + lane*16.
__device__ inline void gl_lds16(const void* g, void* l) {
    __builtin_amdgcn_global_load_lds(
        (const __attribute__((address_space(1))) unsigned int*)g,
        (__attribute__((address_space(3))) unsigned int*)l, 16, 0, 0);
}

// ============================ FAST PATH ============================
// dispatch 1: memset (pooled + scat_pos, 20.5 KB)
// dispatch 2: k_prep  = scatter | W transpose+cast   (x-cast pass DELETED)
// dispatch 3: k_g1    = grouped GEMM1: A reg-staged fp32->bf16, B gl_lds, dbuf
// dispatch 4: k_g2    = grouped GEMM2 + relu colsum -> pooled
// dispatch 5: k_head  = fc + gated attention (fused, direct a_logit store)
// dispatch 6: k_final

__global__ __launch_bounds__(256) void k_prep(
    const int* __restrict__ cid, int n,
    const float* __restrict__ W1, const float* __restrict__ W2,
    ushort_t* __restrict__ W1t, ushort_t* __restrict__ W2t,
    int nw,
    int* __restrict__ scat_pos, int* __restrict__ bucket)
{
    int bid = blockIdx.x;
    int t = threadIdx.x;

    if (bid < NSC) {                      // direct-atomic scatter into padded buckets
        int lane = t & 63;
        for (int i = bid * 256 + t; i < n; i += NSC * 256) {
            int c = cid[i];
            #pragma unroll
            for (int cc = 0; cc < CNUM; cc++) {
                unsigned long long mask = __ballot(c == cc);
                if (mask == 0ull) continue;
                int leader = __ffsll(mask) - 1;
                int basep = 0;
                if (lane == leader) basep = atomicAdd(&scat_pos[cc], __popcll(mask));
                basep = __shfl(basep, leader, 64);
                if (c == cc) {
                    int rank = __popcll(mask & ((1ull << lane) - 1ull));
                    bucket[cc * n + basep + rank] = i;
                }
            }
        }
        return;
    }
    bid -= NSC;

    if (bid < nw) {                       // transpose+cast W1,W2 -> n-major bf16
        __shared__ float tile[64][65];
        int z = bid >> 7;
        int kx = (bid & 127) >> 3;
        int ny = bid & 7;
        const float* src; ushort_t* dst; int K;
        if (z < CNUM) { K = DIN; src = W1 + (size_t)z * K * DH; dst = W1t + (size_t)z * DH * K; }
        else          { K = DH;  src = W2 + (size_t)(z - CNUM) * K * DH; dst = W2t + (size_t)(z - CNUM) * DH * K; }
        int k0 = kx * 64;
        if (k0 >= K) return;
        int n0 = ny * 64;
        int rr = t >> 4;
        int cc = (t & 15) * 4;
        #pragma unroll
        for (int i = 0; i < 4; i++) {
            int row = rr + 16 * i;
            float4 v = *(const float4*)(src + (size_t)(k0 + row) * DH + n0 + cc);
            tile[row][cc + 0] = v.x; tile[row][cc + 1] = v.y;
            tile[row][cc + 2] = v.z; tile[row][cc + 3] = v.w;
        }
        __syncthreads();
        #pragma unroll
        for (int i = 0; i < 4; i++) {
            int nrow = rr + 16 * i;
            ushort4 o = make_ushort4(f2bf(tile[cc + 0][nrow]), f2bf(tile[cc + 1][nrow]),
                                     f2bf(tile[cc + 2][nrow]), f2bf(tile[cc + 3][nrow]));
            *(ushort4*)(dst + (size_t)(n0 + nrow) * K + k0 + cc) = o;
        }
    }
}

// ------- shared pieces for the 64x64, BK=64 double-buffered GEMMs -------
// XOR chunk swizzle: 16B-chunk index ^= (row&7); identical on write and read.

__device__ inline void awrite(ushort_t* A, int o0, int o1,
                              const float4& r0, const float4& r1,
                              const float4& r2, const float4& r3)
{
    uint4 w0, w1;
    w0.x = pkbf(r0.x, r0.y); w0.y = pkbf(r0.z, r0.w);
    w0.z = pkbf(r1.x, r1.y); w0.w = pkbf(r1.z, r1.w);
    w1.x = pkbf(r2.x, r2.y); w1.y = pkbf(r2.z, r2.w);
    w1.z = pkbf(r3.x, r3.y); w1.w = pkbf(r3.z, r3.w);
    *(uint4*)(A + o0) = w0;
    *(uint4*)(A + o1) = w1;
}

// tile mapping: bijective XCD remap (T1) then counts-prefix -> (cluster, m0)
// 64-row m-tiles, 64-col n-tiles (NTILES = DH/64 = 8).
__device__ inline int tile_decode(int bid, int MAXT, const int* counts,
                                  int& c, int& m0, int& tile_n)
{
    int mt, nt;
    if ((MAXT & 7) == 0) {
        int mtpx = MAXT >> 3;
        int xcd = bid & 7, j = bid >> 3;
        nt = j / mtpx;                       // all n-tiles of an m-chunk on one XCD
        mt = xcd * mtpx + (j - nt * mtpx);
    } else { mt = bid >> 3; nt = bid & 7; }

    int rem = mt;
    c = 0;
    #pragma unroll
    for (int cc = 0; cc < CNUM; cc++) {
        int tc = (counts[cc] + 63) >> 6;
        if (rem < tc) { c = cc; m0 = rem * 64; tile_n = nt * 64; return 1; }
        rem -= tc;
    }
    return 0;
}

// ---------------- GEMM1: A reg-staged from fp32 x (indirect), B gl_lds ----------------

__global__ __launch_bounds__(256, 4) void k_g1(
    const float* __restrict__ x, const ushort_t* __restrict__ W1t,
    const float* __restrict__ b1, const int* __restrict__ bucket,
    const int* __restrict__ counts, int n, int MAXT,
    ushort_t* __restrict__ H1)
{
    __shared__ ushort_t As[2][64][64];
    __shared__ ushort_t Bs[2][64][64];

    int c, m0, tile_n;
    if (!tile_decode(blockIdx.x, MAXT, counts, c, m0, tile_n)) return;
    int cnt = counts[c];

    int t = threadIdx.x;
    int lane = t & 63;
    int w = t >> 6, wr = w >> 1, wc = w & 1;
    int m = lane & 15, quad = lane >> 4;

    // A reg-staging: thread -> row ar = t>>2, float-seg (t&3)*16
    int ar = t >> 2;
    int aseg = (t & 3) * 16;
    int ga = m0 + ar; if (ga > cnt - 1) ga = cnt - 1;
    const float* aSrc = x + (size_t)bucket[c * n + ga] * DIN + aseg;
    int c0 = (t & 3) * 2;
    int awo0 = ar * 64 + ((c0    ) ^ (ar & 7)) * 8;
    int awo1 = ar * 64 + ((c0 + 1) ^ (ar & 7)) * 8;

    // B gl_lds: rows rb = t>>3 (+0/+32), pre-swizzled global source, linear dst
    int rb = t >> 3;
    int swz = ((t & 7) ^ (rb & 7)) * 8;
    const ushort_t* bSrc0 = W1t + ((size_t)c * DH + tile_n +  0 + rb) * DIN + swz;
    const ushort_t* bSrc1 = W1t + ((size_t)c * DH + tile_n + 32 + rb) * DIN + swz;

    f32x4 acc[2][2] = {};
    float4 r0, r1, r2, r3;

    // prologue: tile 0 -> buf0
    r0 = *(const float4*)(aSrc + 0);  r1 = *(const float4*)(aSrc + 4);
    r2 = *(const float4*)(aSrc + 8);  r3 = *(const float4*)(aSrc + 12);
    gl_lds16(bSrc0, &Bs[0][0][0]  + t * 8);
    gl_lds16(bSrc1, &Bs[0][32][0] + t * 8);
    awrite(&As[0][0][0], awo0, awo1, r0, r1, r2, r3);
    asm volatile("s_waitcnt lgkmcnt(0)" ::: "memory");
    asm volatile("s_waitcnt vmcnt(0)" ::: "memory");
    // first loop iteration's barrier publishes buf0

    #pragma unroll 2
    for (int kt = 0; kt < DIN / 64; kt++) {
        int cur = kt & 1, nxt = cur ^ 1;
        if (kt + 1 < DIN / 64) {
            const float* ap = aSrc + (kt + 1) * 64;
            r0 = *(const float4*)(ap + 0);  r1 = *(const float4*)(ap + 4);
            r2 = *(const float4*)(ap + 8);  r3 = *(const float4*)(ap + 12);
            gl_lds16(bSrc0 + (kt + 1) * 64, &Bs[nxt][0][0]  + t * 8);
            gl_lds16(bSrc1 + (kt + 1) * 64, &Bs[nxt][32][0] + t * 8);
            asm volatile("s_waitcnt vmcnt(6)" ::: "memory");   // tile kt's B resident
        } else {
            asm volatile("s_waitcnt vmcnt(0)" ::: "memory");
        }
        __builtin_amdgcn_sched_barrier(0);
        __builtin_amdgcn_s_barrier();                          // buf[cur] published
        __builtin_amdgcn_sched_barrier(0);

        bf16x8 a[2][2], b[2][2];
        #pragma unroll
        for (int ks = 0; ks < 2; ks++) {
            int chunk = ((ks * 4 + quad) ^ (m & 7)) * 8;
            #pragma unroll
            for (int mf = 0; mf < 2; mf++)
                a[ks][mf] = *(const bf16x8*)(&As[cur][0][0] + (32 * wr + 16 * mf + m) * 64 + chunk);
            #pragma unroll
            for (int nf = 0; nf < 2; nf++)
                b[ks][nf] = *(const bf16x8*)(&Bs[cur][0][0] + (32 * wc + 16 * nf + m) * 64 + chunk);
        }
        asm volatile("s_waitcnt lgkmcnt(0)" ::: "memory");     // own reads complete
        __builtin_amdgcn_sched_barrier(0);
        __builtin_amdgcn_s_barrier();                          // all reads of buf[cur] done
        __builtin_amdgcn_sched_barrier(0);

        #pragma unroll
        for (int ks = 0; ks < 2; ks++)
            #pragma unroll
            for (int mf = 0; mf < 2; mf++)
                #pragma unroll
                for (int nf = 0; nf < 2; nf++)
                    acc[mf][nf] = __builtin_amdgcn_mfma_f32_16x16x32_bf16(a[ks][mf], b[ks][nf], acc[mf][nf], 0, 0, 0);

        if (kt + 1 < DIN / 64) {
            awrite(&As[nxt][0][0], awo0, awo1, r0, r1, r2, r3);   // tile kt+1's A
            asm volatile("s_waitcnt lgkmcnt(0)" ::: "memory");    // writes committed
        }
    }

    int col0 = tile_n + 32 * wc;
    #pragma unroll
    for (int nf = 0; nf < 2; nf++) {
        int col = col0 + 16 * nf + m;
        float bv = b1[c * DH + col];
        #pragma unroll
        for (int mf = 0; mf < 2; mf++) {
            int rowb = m0 + 32 * wr + 16 * mf + quad * 4;
            #pragma unroll
            for (int r = 0; r < 4; r++) {
                int row = rowb + r;
                if (row < cnt)
                    H1[((size_t)c * n + row) * DH + col] = f2bf(fmaxf(acc[mf][nf][r] + bv, 0.f));
            }
        }
    }
}

// ---------------- GEMM2: both operands bf16 via gl_lds (unchanged core) ----------------

__device__ inline void stage4(
    const ushort_t* a0, const ushort_t* a1,
    const ushort_t* b0, const ushort_t* b1,
    int ko, ushort_t* As, ushort_t* Bs, int t)
{
    gl_lds16(a0 + ko, As + 0 * 2048 + t * 8);
    gl_lds16(a1 + ko, As + 1 * 2048 + t * 8);
    gl_lds16(b0 + ko, Bs + 0 * 2048 + t * 8);
    gl_lds16(b1 + ko, Bs + 1 * 2048 + t * 8);
}

__device__ inline void mfma_tile64(const ushort_t* As, const ushort_t* Bs,
                                   f32x4 (&acc)[2][2], int wr, int wc, int m, int quad)
{
    bf16x8 a[2][2], b[2][2];
    #pragma unroll
    for (int ks = 0; ks < 2; ks++) {
        int chunk = ((ks * 4 + quad) ^ (m & 7)) * 8;
        #pragma unroll
        for (int mf = 0; mf < 2; mf++)
            a[ks][mf] = *(const bf16x8*)(As + (32 * wr + 16 * mf + m) * 64 + chunk);
        #pragma unroll
        for (int nf = 0; nf < 2; nf++)
            b[ks][nf] = *(const bf16x8*)(Bs + (32 * wc + 16 * nf + m) * 64 + chunk);
    }
    asm volatile("s_waitcnt lgkmcnt(0)" ::: "memory");
    __builtin_amdgcn_sched_barrier(0);
    __builtin_amdgcn_s_barrier();
    __builtin_amdgcn_sched_barrier(0);
    #pragma unroll
    for (int ks = 0; ks < 2; ks++)
        #pragma unroll
        for (int mf = 0; mf < 2; mf++)
            #pragma unroll
            for (int nf = 0; nf < 2; nf++)
                acc[mf][nf] = __builtin_amdgcn_mfma_f32_16x16x32_bf16(a[ks][mf], b[ks][nf], acc[mf][nf], 0, 0, 0);
}

__device__ inline void gemm_loop64(
    const ushort_t* a0, const ushort_t* a1,
    const ushort_t* b0, const ushort_t* b1,
    int KT, f32x4 (&acc)[2][2], ushort_t* As, ushort_t* Bs)
{
    int t = threadIdx.x;
    int lane = t & 63;
    int w = t >> 6, wr = w >> 1, wc = w & 1;
    int m = lane & 15, quad = lane >> 4;

    stage4(a0, a1, b0, b1, 0, As, Bs, t);                       // tile 0 -> buf0
    for (int kt = 0; kt < KT; kt += 2) {
        stage4(a0, a1, b0, b1, (kt + 1) * 64, As + 4096, Bs + 4096, t);
        asm volatile("s_waitcnt vmcnt(4)" ::: "memory");        // tile kt resident
        __builtin_amdgcn_sched_barrier(0);
        __builtin_amdgcn_s_barrier();
        __builtin_amdgcn_sched_barrier(0);
        mfma_tile64(As, Bs, acc, wr, wc, m, quad);

        if (kt + 2 < KT) {
            stage4(a0, a1, b0, b1, (kt + 2) * 64, As, Bs, t);
            asm volatile("s_waitcnt vmcnt(4)" ::: "memory");
        } else {
            asm volatile("s_waitcnt vmcnt(0)" ::: "memory");
        }
        __builtin_amdgcn_sched_barrier(0);
        __builtin_amdgcn_s_barrier();
        __builtin_amdgcn_sched_barrier(0);
        mfma_tile64(As + 4096, Bs + 4096, acc, wr, wc, m, quad);
    }
}

__global__ __launch_bounds__(256, 4) void k_g2(
    const ushort_t* __restrict__ H1, const ushort_t* __restrict__ W2t,
    const float* __restrict__ b2, const int* __restrict__ counts, int n, int MAXT,
    float* __restrict__ pooled)
{
    __shared__ ushort_t As[2][64][64];
    __shared__ ushort_t Bs[2][64][64];

    int c, m0, tile_n;
    if (!tile_decode(blockIdx.x, MAXT, counts, c, m0, tile_n)) return;
    int cnt = counts[c];

    int t = threadIdx.x;
    int rr = t >> 3;
    int swz = ((t & 7) ^ (rr & 7)) * 8;

    const ushort_t* aP[2];
    const ushort_t* bP[2];
    #pragma unroll
    for (int s = 0; s < 2; s++) {
        int ra = m0 + s * 32 + rr;
        if (ra > cnt - 1) ra = cnt - 1;
        aP[s] = H1 + ((size_t)c * n + ra) * DH + swz;
        bP[s] = W2t + ((size_t)c * DH + tile_n + s * 32 + rr) * DH + swz;
    }

    f32x4 acc[2][2] = {};
    gemm_loop64(aP[0], aP[1], bP[0], bP[1], DH / 64, acc, &As[0][0][0], &Bs[0][0][0]);

    int lane = t & 63;
    int w = t >> 6, wr = w >> 1, wc = w & 1;
    int m = lane & 15, quad = lane >> 4;
    int col0 = tile_n + 32 * wc;
    #pragma unroll
    for (int nf = 0; nf < 2; nf++) {
        int col = col0 + 16 * nf + m;
        float bv = b2[c * DH + col];
        float s = 0.f;
        #pragma unroll
        for (int mf = 0; mf < 2; mf++) {
            int rowb = m0 + 32 * wr + 16 * mf + quad * 4;
            #pragma unroll
            for (int r = 0; r < 4; r++) {
                int row = rowb + r;
                if (row < cnt) s += fmaxf(acc[mf][nf][r] + bv, 0.f);
            }
        }
        s += __shfl_xor(s, 16);
        s += __shfl_xor(s, 32);
        if (quad == 0) atomicAdd(&pooled[c * DH + col], s);
    }
}

// ---------------- fused head: fc + gated attention per cluster ----------------

__global__ __launch_bounds__(512) void k_head(
    const float* __restrict__ pooled, const int* __restrict__ counts,
    const float* __restrict__ Wfc, const float* __restrict__ bfc,
    const float* __restrict__ Wa, const float* __restrict__ ba,
    const float* __restrict__ Wb, const float* __restrict__ bb,
    const float* __restrict__ Wc, const float* __restrict__ bc,
    float* __restrict__ hfc, float* __restrict__ a_logit)
{
    int c = blockIdx.x;
    int t = threadIdx.x;
    __shared__ float ps[DH];
    __shared__ float hf[DH];
    __shared__ float ra[2][DATT], rb[2][DATT];
    __shared__ float wred[4];

    float cnt = fmaxf((float)counts[c], 1.f);
    ps[t] = pooled[c * DH + t] / cnt;
    __syncthreads();

    float a0 = 0.f, a1 = 0.f;
    #pragma unroll 4
    for (int k = 0; k < DH; k += 2) {
        a0 = fmaf(ps[k],     Wfc[(size_t)k * DH + t],       a0);
        a1 = fmaf(ps[k + 1], Wfc[(size_t)(k + 1) * DH + t], a1);
    }
    float h = fmaxf(a0 + a1 + bfc[t], 0.f);
    hf[t] = h;
    hfc[c * DH + t] = h;
    __syncthreads();

    int d = t & 255, half = t >> 8;
    float ga = 0.f, gb = 0.f;
    #pragma unroll 4
    for (int k = half * 256; k < half * 256 + 256; k++) {
        float hh = hf[k];
        ga = fmaf(hh, Wa[(size_t)k * DATT + d], ga);
        gb = fmaf(hh, Wb[(size_t)k * DATT + d], gb);
    }
    ra[half][d] = ga;
    rb[half][d] = gb;
    __syncthreads();

    if (t < DATT) {
        float sa = ra[0][t] + ra[1][t] + ba[t];
        float sb = rb[0][t] + rb[1][t] + bb[t];
        float g = tanhf(sa) * (1.f / (1.f + expf(-sb)));
        float p = g * Wc[t];
        #pragma unroll
        for (int off = 32; off >= 1; off >>= 1) p += __shfl_down(p, off, 64);
        if ((t & 63) == 0) wred[t >> 6] = p;
    }
    __syncthreads();
    if (t == 0) a_logit[c] = bc[0] + wred[0] + wred[1] + wred[2] + wred[3];
}

__global__ __launch_bounds__(1024) void k_final(
    const float* __restrict__ hfc, const float* __restrict__ a_logit,
    const float* __restrict__ Wr, const float* __restrict__ br,
    const float* __restrict__ Wcls, const float* __restrict__ bcls,
    float* __restrict__ out)
{
    int t = threadIdx.x;
    __shared__ float hp[DH];
    __shared__ float r1[4][DATT];
    __shared__ float hr[DATT];
    __shared__ float wred[4][NCLS];

    float al[CNUM];
    float m = -1e30f;
    #pragma unroll
    for (int c = 0; c < CNUM; c++) { al[c] = a_logit[c]; m = fmaxf(m, al[c]); }
    float s = 0.f;
    #pragma unroll
    for (int c = 0; c < CNUM; c++) { al[c] = expf(al[c] - m); s += al[c]; }
    float inv = 1.f / s;

    if (t < DH) {
        float v = 0.f;
        #pragma unroll
        for (int c = 0; c < CNUM; c++) v = fmaf(al[c] * inv, hfc[c * DH + t], v);
        hp[t] = v;
    }
    __syncthreads();

    int d = t & 255;
    int ks = t >> 8;
    float acc = 0.f;
    #pragma unroll 8
    for (int k = ks * 128; k < ks * 128 + 128; k++)
        acc = fmaf(hp[k], Wr[(size_t)k * DATT + d], acc);
    r1[ks][d] = acc;
    __syncthreads();
    if (t < DATT)
        hr[t] = fmaxf(r1[0][t] + r1[1][t] + r1[2][t] + r1[3][t] + br[t], 0.f);
    __syncthreads();

    if (t < 256) {
        float h = hr[t];
        #pragma unroll
        for (int cls = 0; cls < NCLS; cls++) {
            float p = h * Wcls[(size_t)t * NCLS + cls];
            #pragma unroll
            for (int off = 32; off >= 1; off >>= 1) p += __shfl_down(p, off, 64);
            if ((t & 63) == 0) wred[t >> 6][cls] = p;
        }
    }
    __syncthreads();
    if (t == 0) {
        float lg[NCLS];
        #pragma unroll
        for (int cls = 0; cls < NCLS; cls++)
            lg[cls] = bcls[cls] + wred[0][cls] + wred[1][cls] + wred[2][cls] + wred[3][cls];
        float mm = lg[0];
        #pragma unroll
        for (int i = 1; i < NCLS; i++) mm = fmaxf(mm, lg[i]);
        float ss = 0.f, pr[NCLS];
        #pragma unroll
        for (int i = 0; i < NCLS; i++) { pr[i] = expf(lg[i] - mm); ss += pr[i]; }
        int am = 0; float best = lg[0];
        #pragma unroll
        for (int i = 1; i < NCLS; i++) if (lg[i] > best) { best = lg[i]; am = i; }
        #pragma unroll
        for (int i = 0; i < NCLS; i++) out[i] = lg[i];
        #pragma unroll
        for (int i = 0; i < NCLS; i++) out[4 + i] = pr[i] / ss;
        out[8] = (float)am;
    }
}

// ==================== FALLBACK PATH (small ws) — unchanged ====================

__global__ __launch_bounds__(256) void k_hist(
    const int* __restrict__ cid, int n, const float* __restrict__ bc,
    int* __restrict__ counts_part, float* __restrict__ pooled,
    float* __restrict__ a_logit, int* __restrict__ scat_pos)
{
    int bid = blockIdx.x;
    int t = threadIdx.x;

    if (bid < NH) {
        __shared__ int h[CNUM];
        int lane = t & 63;
        if (t < CNUM) h[t] = 0;
        __syncthreads();
        for (int i = bid * 256 + t; i < n; i += NH * 256) {
            int c = cid[i];
            #pragma unroll
            for (int cc = 0; cc < CNUM; cc++) {
                unsigned long long mask = __ballot(c == cc);
                if (mask == 0ull) continue;
                if (lane == (__ffsll(mask) - 1)) atomicAdd(&h[cc], __popcll(mask));
            }
        }
        __syncthreads();
        if (t < CNUM) counts_part[bid * 16 + t] = h[t];
        return;
    }

    for (int i = t; i < CNUM * DH; i += 256) pooled[i] = 0.f;
    if (t < CNUM) a_logit[t] = bc[0];
    if (t < CNUM) scat_pos[t] = 0;
}

__global__ __launch_bounds__(256) void k_scat_fb(
    const int* __restrict__ cid, int n, const int* __restrict__ counts_part,
    int* __restrict__ counts, int* __restrict__ offsets,
    int* __restrict__ scat_pos, int* __restrict__ bucket)
{
    int bid = blockIdx.x;
    int t = threadIdx.x;
    __shared__ int cnts[CNUM], off[CNUM];
    if (t < CNUM) {
        int s = 0;
        #pragma unroll 8
        for (int b = 0; b < NH; b++) s += counts_part[b * 16 + t];
        cnts[t] = s;
    }
    __syncthreads();
    if (t == 0) {
        int a = 0;
        for (int c = 0; c < CNUM; c++) { off[c] = a; a += cnts[c]; }
        if (bid == 0) {
            int aa = 0;
            for (int c = 0; c < CNUM; c++) { offsets[c] = aa; counts[c] = cnts[c]; aa += cnts[c]; }
            offsets[CNUM] = aa;
        }
    }
    __syncthreads();
    int lane = t & 63;
    for (int i = bid * 256 + t; i < n; i += NSC * 256) {
        int c = cid[i];
        #pragma unroll
        for (int cc = 0; cc < CNUM; cc++) {
            unsigned long long mask = __ballot(c == cc);
            if (mask == 0ull) continue;
            int leader = __ffsll(mask) - 1;
            int basep = 0;
            if (lane == leader) basep = atomicAdd(&scat_pos[cc], __popcll(mask));
            basep = __shfl(basep, leader, 64);
            if (c == cc) {
                int rank = __popcll(mask & ((1ull << lane) - 1ull));
                bucket[off[cc] + basep + rank] = i;
            }
        }
    }
}

__global__ __launch_bounds__(256) void k_fc2(
    const float* __restrict__ pooled, const int* __restrict__ counts,
    const float* __restrict__ Wfc, const float* __restrict__ bfc,
    float* __restrict__ hfc)
{
    int c = blockIdx.x;
    int c0 = blockIdx.y * 64;
    __shared__ float ps[DH];
    __shared__ float red[4][64];
    int t = threadIdx.x;
    float cnt = fmaxf((float)counts[c], 1.f);
    ps[t] = pooled[c * DH + t] / cnt;
    ps[t + 256] = pooled[c * DH + t + 256] / cnt;
    __syncthreads();
    int col = c0 + (t & 63);
    int ks = t >> 6;
    float acc = 0.f;
    #pragma unroll 8
    for (int k = ks * 128; k < ks * 128 + 128; k++)
        acc = fmaf(ps[k], Wfc[(size_t)k * DH + col], acc);
    red[ks][t & 63] = acc;
    __syncthreads();
    if (t < 64) {
        float v = red[0][t] + red[1][t] + red[2][t] + red[3][t] + bfc[c0 + t];
        hfc[c * DH + c0 + t] = fmaxf(v, 0.f);
    }
}

__global__ __launch_bounds__(256) void k_gate2(
    const float* __restrict__ hfc,
    const float* __restrict__ Wa, const float* __restrict__ ba,
    const float* __restrict__ Wb, const float* __restrict__ bb,
    const float* __restrict__ Wc,
    float* __restrict__ a_logit)
{
    int c = blockIdx.x;
    int d0 = blockIdx.y * 64;
    __shared__ float hf[DH];
    __shared__ float ra[4][64], rb[4][64];
    int t = threadIdx.x;
    hf[t] = hfc[c * DH + t];
    hf[t + 256] = hfc[c * DH + t + 256];
    __syncthreads();
    int d = d0 + (t & 63);
    int ks = t >> 6;
    float ga = 0.f, gb = 0.f;
    #pragma unroll 8
    for (int k = ks * 128; k < ks * 128 + 128; k++) {
        float h = hf[k];
        ga = fmaf(h, Wa[(size_t)k * DATT + d], ga);
        gb = fmaf(h, Wb[(size_t)k * DATT + d], gb);
    }
    ra[ks][t & 63] = ga;
    rb[ks][t & 63] = gb;
    __syncthreads();
    if (t < 64) {
        float sa = ra[0][t] + ra[1][t] + ra[2][t] + ra[3][t] + ba[d0 + t];
        float sb = rb[0][t] + rb[1][t] + rb[2][t] + rb[3][t] + bb[d0 + t];
        float g = tanhf(sa) * (1.f / (1.f + expf(-sb)));
        float p = g * Wc[d0 + t];
        #pragma unroll
        for (int off = 32; off >= 1; off >>= 1) p += __shfl_down(p, off, 64);
        if (t == 0) atomicAdd(&a_logit[c], p);
    }
}

#define MT 64
#define NT 128
#define KT 32

__global__ __launch_bounds__(256) void k_gemm1(
    const float* __restrict__ x, const float* __restrict__ W1, const float* __restrict__ b1,
    const int* __restrict__ bucket, const int* __restrict__ offsets, const int* __restrict__ counts,
    float* __restrict__ H1)
{
    int c = blockIdx.z;
    int cnt = counts[c];
    int m0 = blockIdx.x * MT;
    if (m0 >= cnt) return;
    int rows = min(MT, cnt - m0);
    int n0 = blockIdx.y * NT;
    int base = offsets[c];

    __shared__ float As[KT][MT + 4];
    __shared__ float Bs[KT][NT];

    int t = threadIdx.x;
    int tr = t >> 4;
    int tc = t & 15;
    int lr = t >> 2;
    int lk = (t & 3) * 8;
    const float* xrow = nullptr;
    if (lr < rows) xrow = x + (size_t)bucket[base + m0 + lr] * DIN;

    float acc[4][8];
    #pragma unroll
    for (int i = 0; i < 4; i++)
        #pragma unroll
        for (int j = 0; j < 8; j++) acc[i][j] = 0.f;

    const float* Wp = W1 + (size_t)c * DIN * DH + n0;

    for (int k0 = 0; k0 < DIN; k0 += KT) {
        __syncthreads();
        if (xrow) {
            float4 v0 = *(const float4*)(xrow + k0 + lk);
            float4 v1 = *(const float4*)(xrow + k0 + lk + 4);
            As[lk + 0][lr] = v0.x; As[lk + 1][lr] = v0.y;
            As[lk + 2][lr] = v0.z; As[lk + 3][lr] = v0.w;
            As[lk + 4][lr] = v1.x; As[lk + 5][lr] = v1.y;
            As[lk + 6][lr] = v1.z; As[lk + 7][lr] = v1.w;
        } else {
            #pragma unroll
            for (int i = 0; i < 8; i++) As[lk + i][lr] = 0.f;
        }
        #pragma unroll
        for (int i = 0; i < 4; i++) {
            int idx = i * 256 + t;
            int kk = idx >> 5;
            int cv = idx & 31;
            *(float4*)&Bs[kk][cv * 4] = *(const float4*)(Wp + (size_t)(k0 + kk) * DH + cv * 4);
        }
        __syncthreads();
        #pragma unroll
        for (int k = 0; k < KT; k++) {
            float4 av  = *(const float4*)&As[k][4 * tr];
            float4 bv0 = *(const float4*)&Bs[k][4 * tc];
            float4 bv1 = *(const float4*)&Bs[k][64 + 4 * tc];
            float a[4] = {av.x, av.y, av.z, av.w};
            float b[8] = {bv0.x, bv0.y, bv0.z, bv0.w, bv1.x, bv1.y, bv1.z, bv1.w};
            #pragma unroll
            for (int i = 0; i < 4; i++)
                #pragma unroll
                for (int j = 0; j < 8; j++)
                    acc[i][j] = fmaf(a[i], b[j], acc[i][j]);
        }
    }

    #pragma unroll
    for (int i = 0; i < 4; i++) {
        int r = 4 * tr + i;
        if (r < rows) {
            size_t grow = (size_t)(base + m0 + r) * DH;
            #pragma unroll
            for (int j = 0; j < 8; j++) {
                int cidx = (j < 4) ? (4 * tc + j) : (64 + 4 * tc + (j - 4));
                int col = n0 + cidx;
                float v = acc[i][j] + b1[c * DH + col];
                H1[grow + col] = fmaxf(v, 0.f);
            }
        }
    }
}

__global__ __launch_bounds__(256) void k_gemm2(
    const float* __restrict__ H1, const float* __restrict__ W2, const float* __restrict__ b2,
    const int* __restrict__ offsets, const int* __restrict__ counts,
    float* __restrict__ pooled)
{
    int c = blockIdx.z;
    int cnt = counts[c];
    int m0 = blockIdx.x * MT;
    if (m0 >= cnt) return;
    int rows = min(MT, cnt - m0);
    int n0 = blockIdx.y * NT;
    int base = offsets[c];

    __shared__ float As[KT][MT + 4];
    __shared__ float Bs[KT][NT];
    __shared__ float red[16][NT];

    int t = threadIdx.x;
    int tr = t >> 4;
    int tc = t & 15;
    int lr = t >> 2;
    int lk = (t & 3) * 8;
    const float* arow = (lr < rows) ? (H1 + (size_t)(base + m0 + lr) * DH) : nullptr;

    float acc[4][8];
    #pragma unroll
    for (int i = 0; i < 4; i++)
        #pragma unroll
        for (int j = 0; j < 8; j++) acc[i][j] = 0.f;

    const float* Wp = W2 + (size_t)c * DH * DH + n0;

    for (int k0 = 0; k0 < DH; k0 += KT) {
        __syncthreads();
        if (arow) {
            float4 v0 = *(const float4*)(arow + k0 + lk);
            float4 v1 = *(const float4*)(arow + k0 + lk + 4);
            As[lk + 0][lr] = v0.x; As[lk + 1][lr] = v0.y;
            As[lk + 2][lr] = v0.z; As[lk + 3][lr] = v0.w;
            As[lk + 4][lr] = v1.x; As[lk + 5][lr] = v1.y;
            As[lk + 6][lr] = v1.z; As[lk + 7][lr] = v1.w;
        } else {
            #pragma unroll
            for (int i = 0; i < 8; i++) As[lk + i][lr] = 0.f;
        }
        #pragma unroll
        for (int i = 0; i < 4; i++) {
            int idx = i * 256 + t;
            int kk = idx >> 5;
            int cv = idx & 31;
            *(float4*)&Bs[kk][cv * 4] = *(const float4*)(Wp + (size_t)(k0 + kk) * DH + cv * 4);
        }
        __syncthreads();
        #pragma unroll
        for (int k = 0; k < KT; k++) {
            float4 av  = *(const float4*)&As[k][4 * tr];
            float4 bv0 = *(const float4*)&Bs[k][4 * tc];
            float4 bv1 = *(const float4*)&Bs[k][64 + 4 * tc];
            float a[4] = {av.x, av.y, av.z, av.w};
            float b[8] = {bv0.x, bv0.y, bv0.z, bv0.w, bv1.x, bv1.y, bv1.z, bv1.w};
            #pragma unroll
            for (int i = 0; i < 4; i++)
                #pragma unroll
                for (int j = 0; j < 8; j++)
                    acc[i][j] = fmaf(a[i], b[j], acc[i][j]);
        }
    }

    __syncthreads();
    #pragma unroll
    for (int j = 0; j < 8; j++) {
        int cidx = (j < 4) ? (4 * tc + j) : (64 + 4 * tc + (j - 4));
        float bias = b2[c * DH + n0 + cidx];
        float s = 0.f;
        #pragma unroll
        for (int i = 0; i < 4; i++) {
            if (4 * tr + i < rows) s += fmaxf(acc[i][j] + bias, 0.f);
        }
        red[tr][cidx] = s;
    }
    __syncthreads();
    if (t < NT) {
        float s = 0.f;
        #pragma unroll
        for (int r = 0; r < 16; r++) s += red[r][t];
        atomicAdd(&pooled[c * DH + n0 + t], s);
    }
}

// ---------------- launcher ----------------

extern "C" void kernel_launch(void* const* d_in, const int* in_sizes, int n_in,
                              void* d_out, int out_size, void* d_ws, size_t ws_size,
                              hipStream_t stream) {
    (void)n_in; (void)out_size;
    const float* x    = (const float*)d_in[0];
    const int*   cid  = (const int*)d_in[1];
    const float* W1   = (const float*)d_in[2];
    const float* b1   = (const float*)d_in[3];
    const float* W2   = (const float*)d_in[4];
    const float* b2   = (const float*)d_in[5];
    const float* Wfc  = (const float*)d_in[6];
    const float* bfc  = (const float*)d_in[7];
    const float* Wa   = (const float*)d_in[8];
    const float* ba   = (const float*)d_in[9];
    const float* Wb   = (const float*)d_in[10];
    const float* bb   = (const float*)d_in[11];
    const float* Wc   = (const float*)d_in[12];
    const float* bc   = (const float*)d_in[13];
    const float* Wr   = (const float*)d_in[14];
    const float* br   = (const float*)d_in[15];
    const float* Wcls = (const float*)d_in[16];
    const float* bcls = (const float*)d_in[17];
    float* out = (float*)d_out;
    float* ws  = (float*)d_ws;

    int n = in_sizes[1];

    // ---- fast layout ----
    float* pooled   = ws;                          // 5120 f
    int*   scat_pos = (int*)(ws + 5120);           // 16 i (doubles as counts)
    float* a_logit  = ws + 5136;                   // 16 f
    float* hfc      = ws + 5152;                   // 5120 f -> 10272
    int*   bucket   = (int*)(ws + 10272);          // CNUM * n (padded per-cluster)

    size_t big0 = (((size_t)(10272 + (size_t)CNUM * n) * 4) + 255) & ~(size_t)255;
    size_t w1t_bytes = (size_t)CNUM * DH * DIN * 2;
    size_t w2t_bytes = (size_t)CNUM * DH * DH * 2;
    size_t h1_bytes  = (size_t)CNUM * n * DH * 2;  // padded per-cluster rows
    size_t need = big0 + w1t_bytes + w2t_bytes + h1_bytes;

    if (ws_size >= need) {
        ushort_t* W1t = (ushort_t*)((char*)d_ws + big0);
        ushort_t* W2t = (ushort_t*)((char*)d_ws + big0 + w1t_bytes);
        ushort_t* H1  = (ushort_t*)((char*)d_ws + big0 + w1t_bytes + w2t_bytes);

        int nw  = 128 * 2 * CNUM;
        // 64-row m-tiles: sum ceil(cnt/64) <= n/64 + CNUM; round up to mult of 8
        int MAXT = ((n / 64 + CNUM + 1) + 7) & ~7;

        hipMemsetAsync(ws, 0, 5136 * 4, stream);   // pooled + scat_pos
        k_prep<<<NSC + nw, 256, 0, stream>>>(cid, n, W1, W2, W1t, W2t, nw, scat_pos, bucket);
        k_g1<<<8 * MAXT, 256, 0, stream>>>(x, W1t, b1, bucket, scat_pos, n, MAXT, H1);
        k_g2<<<8 * MAXT, 256, 0, stream>>>(H1, W2t, b2, scat_pos, n, MAXT, pooled);
        k_head<<<CNUM, 512, 0, stream>>>(pooled, scat_pos, Wfc, bfc, Wa, ba, Wb, bb, Wc, bc, hfc, a_logit);
        k_final<<<1, 1024, 0, stream>>>(hfc, a_logit, Wr, br, Wcls, bcls, out);
    } else {
        // ---- fallback: old fp32 pipeline, old layout ----
        float* pooledF     = ws + 0;
        int*   countsF     = (int*)(ws + 5120);
        int*   offsetsF    = (int*)(ws + 5136);
        float* a_logitF    = ws + 5168;
        int*   scat_posF   = (int*)(ws + 5184);
        float* hfcF        = ws + 5200;
        int*   counts_part = (int*)(ws + 10320);
        int*   bucketF     = (int*)(ws + 11344);

        k_hist<<<NH + 1, 256, 0, stream>>>(cid, n, bc, counts_part, pooledF, a_logitF, scat_posF);
        k_scat_fb<<<NSC, 256, 0, stream>>>(cid, n, counts_part, countsF, offsetsF, scat_posF, bucketF);

        float* H1f = ws + ((11344 + n + 31) & ~31);
        dim3 gg((n + MT - 1) / MT, DH / NT, CNUM);
        k_gemm1<<<gg, 256, 0, stream>>>(x, W1, b1, bucketF, offsetsF, countsF, H1f);
        k_gemm2<<<gg, 256, 0, stream>>>(H1f, W2, b2, offsetsF, countsF, pooledF);

        k_fc2<<<dim3(CNUM, 8), 256, 0, stream>>>(pooledF, countsF, Wfc, bfc, hfcF);
        k_gate2<<<dim3(CNUM, 4), 256, 0, stream>>>(hfcF, Wa, ba, Wb, bb, Wc, a_logitF);
        k_final<<<1, 1024, 0, stream>>>(hfcF, a_logitF, Wr, br, Wcls, bcls, out);
    }
}

// Round 4
// 239.688 us; speedup vs baseline: 1.1871x; 1.1871x over previous
//
#include <hip/hip_runtime.h>
#include <math.h>

#define DIN 1024
#define DH 512
#define DATT 256
#define CNUM 10
#define NCLS 4
#define NH 64              // histogram blocks (fallback path)
#define NSC 40             // scatter blocks

typedef __attribute__((ext_vector_type(8))) short bf16x8;
typedef __attribute__((ext_vector_type(4))) float f32x4;
typedef unsigned short ushort_t;
typedef unsigned int uint_t;

__device__ inline ushort_t f2bf(float f) {
    uint_t u = __float_as_uint(f);
    u += 0x7FFF + ((u >> 16) & 1);   // RNE
    return (ushort_t)(u >> 16);
}

// packed f32x2 -> bf16x2 (RNE), single VALU op
__device__ inline uint_t pkbf(float lo, float hi) {
    uint_t r;
    asm("v_cvt_pk_bf16_f32 %0, %1, %2" : "=v"(r) : "v"(lo), "v"(hi));
    return r;
}

// async global->LDS, 16B per lane. LDS dst must be wave-uniform base + lane*16.
__device__ inline void gl_lds16(const void* g, void* l) {
    __builtin_amdgcn_global_load_lds(
        (const __attribute__((address_space(1))) unsigned int*)g,
        (__attribute__((address_space(3))) unsigned int*)l, 16, 0, 0);
}

// ============================ FAST PATH ============================
// dispatch 1: memset (pooled + scat_pos)
// dispatch 2: k_prep  = scatter | W transpose+cast
// dispatch 3: k_g1    = grouped GEMM1: A reg-staged fp32->bf16, B gl_lds, dbuf
// dispatch 4: k_g2    = grouped GEMM2 + relu colsum -> pooled
// dispatch 5-7: k_fc2 / k_gate2 / k_final  (80/40/1 blocks — parallelism > fusion,
//               R3 lesson: 10-block fused head = 67us, split tail = ~4us)

__global__ __launch_bounds__(256) void k_prep(
    const int* __restrict__ cid, int n,
    const float* __restrict__ W1, const float* __restrict__ W2,
    ushort_t* __restrict__ W1t, ushort_t* __restrict__ W2t,
    int nw,
    int* __restrict__ scat_pos, int* __restrict__ bucket)
{
    int bid = blockIdx.x;
    int t = threadIdx.x;

    if (bid < NSC) {                      // direct-atomic scatter into padded buckets
        int lane = t & 63;
        for (int i = bid * 256 + t; i < n; i += NSC * 256) {
            int c = cid[i];
            #pragma unroll
            for (int cc = 0; cc < CNUM; cc++) {
                unsigned long long mask = __ballot(c == cc);
                if (mask == 0ull) continue;
                int leader = __ffsll(mask) - 1;
                int basep = 0;
                if (lane == leader) basep = atomicAdd(&scat_pos[cc], __popcll(mask));
                basep = __shfl(basep, leader, 64);
                if (c == cc) {
                    int rank = __popcll(mask & ((1ull << lane) - 1ull));
                    bucket[cc * n + basep + rank] = i;
                }
            }
        }
        return;
    }
    bid -= NSC;

    if (bid < nw) {                       // transpose+cast W1,W2 -> n-major bf16
        __shared__ float tile[64][65];
        int z = bid >> 7;
        int kx = (bid & 127) >> 3;
        int ny = bid & 7;
        const float* src; ushort_t* dst; int K;
        if (z < CNUM) { K = DIN; src = W1 + (size_t)z * K * DH; dst = W1t + (size_t)z * DH * K; }
        else          { K = DH;  src = W2 + (size_t)(z - CNUM) * K * DH; dst = W2t + (size_t)(z - CNUM) * DH * K; }
        int k0 = kx * 64;
        if (k0 >= K) return;
        int n0 = ny * 64;
        int rr = t >> 4;
        int cc = (t & 15) * 4;
        #pragma unroll
        for (int i = 0; i < 4; i++) {
            int row = rr + 16 * i;
            float4 v = *(const float4*)(src + (size_t)(k0 + row) * DH + n0 + cc);
            tile[row][cc + 0] = v.x; tile[row][cc + 1] = v.y;
            tile[row][cc + 2] = v.z; tile[row][cc + 3] = v.w;
        }
        __syncthreads();
        #pragma unroll
        for (int i = 0; i < 4; i++) {
            int nrow = rr + 16 * i;
            ushort4 o = make_ushort4(f2bf(tile[cc + 0][nrow]), f2bf(tile[cc + 1][nrow]),
                                     f2bf(tile[cc + 2][nrow]), f2bf(tile[cc + 3][nrow]));
            *(ushort4*)(dst + (size_t)(n0 + nrow) * K + k0 + cc) = o;
        }
    }
}

// ------- shared pieces for the 64x64, BK=64 double-buffered GEMMs -------
// XOR chunk swizzle: 16B-chunk index ^= (row&7); identical on write and read.

__device__ inline void awrite(ushort_t* A, int o0, int o1,
                              const float4& r0, const float4& r1,
                              const float4& r2, const float4& r3)
{
    uint4 w0, w1;
    w0.x = pkbf(r0.x, r0.y); w0.y = pkbf(r0.z, r0.w);
    w0.z = pkbf(r1.x, r1.y); w0.w = pkbf(r1.z, r1.w);
    w1.x = pkbf(r2.x, r2.y); w1.y = pkbf(r2.z, r2.w);
    w1.z = pkbf(r3.x, r3.y); w1.w = pkbf(r3.z, r3.w);
    *(uint4*)(A + o0) = w0;
    *(uint4*)(A + o1) = w1;
}

// tile mapping: bijective XCD remap (T1) then counts-prefix -> (cluster, m0, H1 base).
// 64-row m-tiles, 64-col n-tiles (NTILES = DH/64 = 8). H1 rows are 64-padded
// per cluster: base(c) = sum_{cc<c} ceil(counts[cc]/64)*64  (compact, ~10.6 MB).
__device__ inline int tile_decode(int bid, int MAXT, const int* counts,
                                  int& c, int& m0, int& tile_n, int& base)
{
    int mt, nt;
    if ((MAXT & 7) == 0) {
        int mtpx = MAXT >> 3;
        int xcd = bid & 7, j = bid >> 3;
        nt = j / mtpx;                       // all n-tiles of an m-chunk on one XCD
        mt = xcd * mtpx + (j - nt * mtpx);
    } else { mt = bid >> 3; nt = bid & 7; }

    int rem = mt;
    c = 0; base = 0;
    #pragma unroll
    for (int cc = 0; cc < CNUM; cc++) {
        int tc = (counts[cc] + 63) >> 6;
        if (rem < tc) { c = cc; m0 = rem * 64; tile_n = nt * 64; return 1; }
        rem -= tc;
        base += tc * 64;
    }
    return 0;
}

// ---------------- GEMM1: A reg-staged from fp32 x (indirect), B gl_lds ----------------

__global__ __launch_bounds__(256, 4) void k_g1(
    const float* __restrict__ x, const ushort_t* __restrict__ W1t,
    const float* __restrict__ b1, const int* __restrict__ bucket,
    const int* __restrict__ counts, int n, int MAXT,
    ushort_t* __restrict__ H1)
{
    __shared__ ushort_t As[2][64][64];
    __shared__ ushort_t Bs[2][64][64];

    int c, m0, tile_n, base;
    if (!tile_decode(blockIdx.x, MAXT, counts, c, m0, tile_n, base)) return;
    int cnt = counts[c];

    int t = threadIdx.x;
    int lane = t & 63;
    int w = t >> 6, wr = w >> 1, wc = w & 1;
    int m = lane & 15, quad = lane >> 4;

    // A reg-staging: thread -> row ar = t>>2, float-seg (t&3)*16
    int ar = t >> 2;
    int aseg = (t & 3) * 16;
    int ga = m0 + ar; if (ga > cnt - 1) ga = cnt - 1;
    const float* aSrc = x + (size_t)bucket[c * n + ga] * DIN + aseg;
    int c0 = (t & 3) * 2;
    int awo0 = ar * 64 + ((c0    ) ^ (ar & 7)) * 8;
    int awo1 = ar * 64 + ((c0 + 1) ^ (ar & 7)) * 8;

    // B gl_lds: rows rb = t>>3 (+0/+32), pre-swizzled global source, linear dst
    int rb = t >> 3;
    int swz = ((t & 7) ^ (rb & 7)) * 8;
    const ushort_t* bSrc0 = W1t + ((size_t)c * DH + tile_n +  0 + rb) * DIN + swz;
    const ushort_t* bSrc1 = W1t + ((size_t)c * DH + tile_n + 32 + rb) * DIN + swz;

    f32x4 acc[2][2] = {};
    float4 r0, r1, r2, r3;

    // prologue: tile 0 -> buf0
    r0 = *(const float4*)(aSrc + 0);  r1 = *(const float4*)(aSrc + 4);
    r2 = *(const float4*)(aSrc + 8);  r3 = *(const float4*)(aSrc + 12);
    gl_lds16(bSrc0, &Bs[0][0][0]  + t * 8);
    gl_lds16(bSrc1, &Bs[0][32][0] + t * 8);
    awrite(&As[0][0][0], awo0, awo1, r0, r1, r2, r3);
    asm volatile("s_waitcnt lgkmcnt(0)" ::: "memory");
    asm volatile("s_waitcnt vmcnt(0)" ::: "memory");
    // first loop iteration's barrier publishes buf0

    #pragma unroll 2
    for (int kt = 0; kt < DIN / 64; kt++) {
        int cur = kt & 1, nxt = cur ^ 1;
        if (kt + 1 < DIN / 64) {
            const float* ap = aSrc + (kt + 1) * 64;
            r0 = *(const float4*)(ap + 0);  r1 = *(const float4*)(ap + 4);
            r2 = *(const float4*)(ap + 8);  r3 = *(const float4*)(ap + 12);
            gl_lds16(bSrc0 + (kt + 1) * 64, &Bs[nxt][0][0]  + t * 8);
            gl_lds16(bSrc1 + (kt + 1) * 64, &Bs[nxt][32][0] + t * 8);
            asm volatile("s_waitcnt vmcnt(6)" ::: "memory");   // tile kt's B resident
        } else {
            asm volatile("s_waitcnt vmcnt(0)" ::: "memory");
        }
        __builtin_amdgcn_sched_barrier(0);
        __builtin_amdgcn_s_barrier();                          // buf[cur] published
        __builtin_amdgcn_sched_barrier(0);

        bf16x8 a[2][2], b[2][2];
        #pragma unroll
        for (int ks = 0; ks < 2; ks++) {
            int chunk = ((ks * 4 + quad) ^ (m & 7)) * 8;
            #pragma unroll
            for (int mf = 0; mf < 2; mf++)
                a[ks][mf] = *(const bf16x8*)(&As[cur][0][0] + (32 * wr + 16 * mf + m) * 64 + chunk);
            #pragma unroll
            for (int nf = 0; nf < 2; nf++)
                b[ks][nf] = *(const bf16x8*)(&Bs[cur][0][0] + (32 * wc + 16 * nf + m) * 64 + chunk);
        }
        asm volatile("s_waitcnt lgkmcnt(0)" ::: "memory");     // own reads complete
        __builtin_amdgcn_sched_barrier(0);
        __builtin_amdgcn_s_barrier();                          // all reads of buf[cur] done
        __builtin_amdgcn_sched_barrier(0);

        #pragma unroll
        for (int ks = 0; ks < 2; ks++)
            #pragma unroll
            for (int mf = 0; mf < 2; mf++)
                #pragma unroll
                for (int nf = 0; nf < 2; nf++)
                    acc[mf][nf] = __builtin_amdgcn_mfma_f32_16x16x32_bf16(a[ks][mf], b[ks][nf], acc[mf][nf], 0, 0, 0);

        if (kt + 1 < DIN / 64) {
            awrite(&As[nxt][0][0], awo0, awo1, r0, r1, r2, r3);   // tile kt+1's A
            asm volatile("s_waitcnt lgkmcnt(0)" ::: "memory");    // writes committed
        }
    }

    int col0 = tile_n + 32 * wc;
    #pragma unroll
    for (int nf = 0; nf < 2; nf++) {
        int col = col0 + 16 * nf + m;
        float bv = b1[c * DH + col];
        #pragma unroll
        for (int mf = 0; mf < 2; mf++) {
            int rowb = m0 + 32 * wr + 16 * mf + quad * 4;
            #pragma unroll
            for (int r = 0; r < 4; r++) {
                int row = rowb + r;
                if (row < cnt)
                    H1[(size_t)(base + row) * DH + col] = f2bf(fmaxf(acc[mf][nf][r] + bv, 0.f));
            }
        }
    }
}

// ---------------- GEMM2: both operands bf16 via gl_lds ----------------

__device__ inline void stage4(
    const ushort_t* a0, const ushort_t* a1,
    const ushort_t* b0, const ushort_t* b1,
    int ko, ushort_t* As, ushort_t* Bs, int t)
{
    gl_lds16(a0 + ko, As + 0 * 2048 + t * 8);
    gl_lds16(a1 + ko, As + 1 * 2048 + t * 8);
    gl_lds16(b0 + ko, Bs + 0 * 2048 + t * 8);
    gl_lds16(b1 + ko, Bs + 1 * 2048 + t * 8);
}

__device__ inline void mfma_tile64(const ushort_t* As, const ushort_t* Bs,
                                   f32x4 (&acc)[2][2], int wr, int wc, int m, int quad)
{
    bf16x8 a[2][2], b[2][2];
    #pragma unroll
    for (int ks = 0; ks < 2; ks++) {
        int chunk = ((ks * 4 + quad) ^ (m & 7)) * 8;
        #pragma unroll
        for (int mf = 0; mf < 2; mf++)
            a[ks][mf] = *(const bf16x8*)(As + (32 * wr + 16 * mf + m) * 64 + chunk);
        #pragma unroll
        for (int nf = 0; nf < 2; nf++)
            b[ks][nf] = *(const bf16x8*)(Bs + (32 * wc + 16 * nf + m) * 64 + chunk);
    }
    asm volatile("s_waitcnt lgkmcnt(0)" ::: "memory");
    __builtin_amdgcn_sched_barrier(0);
    __builtin_amdgcn_s_barrier();
    __builtin_amdgcn_sched_barrier(0);
    #pragma unroll
    for (int ks = 0; ks < 2; ks++)
        #pragma unroll
        for (int mf = 0; mf < 2; mf++)
            #pragma unroll
            for (int nf = 0; nf < 2; nf++)
                acc[mf][nf] = __builtin_amdgcn_mfma_f32_16x16x32_bf16(a[ks][mf], b[ks][nf], acc[mf][nf], 0, 0, 0);
}

__device__ inline void gemm_loop64(
    const ushort_t* a0, const ushort_t* a1,
    const ushort_t* b0, const ushort_t* b1,
    int KT, f32x4 (&acc)[2][2], ushort_t* As, ushort_t* Bs)
{
    int t = threadIdx.x;
    int lane = t & 63;
    int w = t >> 6, wr = w >> 1, wc = w & 1;
    int m = lane & 15, quad = lane >> 4;

    stage4(a0, a1, b0, b1, 0, As, Bs, t);                       // tile 0 -> buf0
    for (int kt = 0; kt < KT; kt += 2) {
        stage4(a0, a1, b0, b1, (kt + 1) * 64, As + 4096, Bs + 4096, t);
        asm volatile("s_waitcnt vmcnt(4)" ::: "memory");        // tile kt resident
        __builtin_amdgcn_sched_barrier(0);
        __builtin_amdgcn_s_barrier();
        __builtin_amdgcn_sched_barrier(0);
        mfma_tile64(As, Bs, acc, wr, wc, m, quad);

        if (kt + 2 < KT) {
            stage4(a0, a1, b0, b1, (kt + 2) * 64, As, Bs, t);
            asm volatile("s_waitcnt vmcnt(4)" ::: "memory");
        } else {
            asm volatile("s_waitcnt vmcnt(0)" ::: "memory");
        }
        __builtin_amdgcn_sched_barrier(0);
        __builtin_amdgcn_s_barrier();
        __builtin_amdgcn_sched_barrier(0);
        mfma_tile64(As + 4096, Bs + 4096, acc, wr, wc, m, quad);
    }
}

__global__ __launch_bounds__(256, 4) void k_g2(
    const ushort_t* __restrict__ H1, const ushort_t* __restrict__ W2t,
    const float* __restrict__ b2, const int* __restrict__ counts, int n, int MAXT,
    float* __restrict__ pooled)
{
    __shared__ ushort_t As[2][64][64];
    __shared__ ushort_t Bs[2][64][64];

    int c, m0, tile_n, base;
    if (!tile_decode(blockIdx.x, MAXT, counts, c, m0, tile_n, base)) return;
    int cnt = counts[c];

    int t = threadIdx.x;
    int rr = t >> 3;
    int swz = ((t & 7) ^ (rr & 7)) * 8;

    const ushort_t* aP[2];
    const ushort_t* bP[2];
    #pragma unroll
    for (int s = 0; s < 2; s++) {
        int ra = m0 + s * 32 + rr;
        if (ra > cnt - 1) ra = cnt - 1;
        aP[s] = H1 + (size_t)(base + ra) * DH + swz;
        bP[s] = W2t + ((size_t)c * DH + tile_n + s * 32 + rr) * DH + swz;
    }

    f32x4 acc[2][2] = {};
    gemm_loop64(aP[0], aP[1], bP[0], bP[1], DH / 64, acc, &As[0][0][0], &Bs[0][0][0]);

    int lane = t & 63;
    int w = t >> 6, wr = w >> 1, wc = w & 1;
    int m = lane & 15, quad = lane >> 4;
    int col0 = tile_n + 32 * wc;
    #pragma unroll
    for (int nf = 0; nf < 2; nf++) {
        int col = col0 + 16 * nf + m;
        float bv = b2[c * DH + col];
        float s = 0.f;
        #pragma unroll
        for (int mf = 0; mf < 2; mf++) {
            int rowb = m0 + 32 * wr + 16 * mf + quad * 4;
            #pragma unroll
            for (int r = 0; r < 4; r++) {
                int row = rowb + r;
                if (row < cnt) s += fmaxf(acc[mf][nf][r] + bv, 0.f);
            }
        }
        s += __shfl_xor(s, 16);
        s += __shfl_xor(s, 32);
        if (quad == 0) atomicAdd(&pooled[c * DH + col], s);
    }
}

// ---------------- parallel epilogue (R0-proven: 80/40/1 blocks) ----------------

__global__ __launch_bounds__(256) void k_fc2(
    const float* __restrict__ pooled, const int* __restrict__ counts,
    const float* __restrict__ Wfc, const float* __restrict__ bfc,
    float* __restrict__ hfc)
{
    int c = blockIdx.x;
    int c0 = blockIdx.y * 64;
    __shared__ float ps[DH];
    __shared__ float red[4][64];
    int t = threadIdx.x;
    float cnt = fmaxf((float)counts[c], 1.f);
    ps[t] = pooled[c * DH + t] / cnt;
    ps[t + 256] = pooled[c * DH + t + 256] / cnt;
    __syncthreads();
    int col = c0 + (t & 63);
    int ks = t >> 6;
    float acc = 0.f;
    #pragma unroll 8
    for (int k = ks * 128; k < ks * 128 + 128; k++)
        acc = fmaf(ps[k], Wfc[(size_t)k * DH + col], acc);
    red[ks][t & 63] = acc;
    __syncthreads();
    if (t < 64) {
        float v = red[0][t] + red[1][t] + red[2][t] + red[3][t] + bfc[c0 + t];
        hfc[c * DH + c0 + t] = fmaxf(v, 0.f);
    }
}

__global__ __launch_bounds__(256) void k_gate2(
    const float* __restrict__ hfc,
    const float* __restrict__ Wa, const float* __restrict__ ba,
    const float* __restrict__ Wb, const float* __restrict__ bb,
    const float* __restrict__ Wc, const float* __restrict__ bc,
    float* __restrict__ a_logit)
{
    int c = blockIdx.x;
    int d0 = blockIdx.y * 64;
    __shared__ float hf[DH];
    __shared__ float ra[4][64], rb[4][64];
    int t = threadIdx.x;
    hf[t] = hfc[c * DH + t];
    hf[t + 256] = hfc[c * DH + t + 256];
    __syncthreads();
    int d = d0 + (t & 63);
    int ks = t >> 6;
    float ga = 0.f, gb = 0.f;
    #pragma unroll 8
    for (int k = ks * 128; k < ks * 128 + 128; k++) {
        float h = hf[k];
        ga = fmaf(h, Wa[(size_t)k * DATT + d], ga);
        gb = fmaf(h, Wb[(size_t)k * DATT + d], gb);
    }
    ra[ks][t & 63] = ga;
    rb[ks][t & 63] = gb;
    __syncthreads();
    if (t < 64) {
        float sa = ra[0][t] + ra[1][t] + ra[2][t] + ra[3][t] + ba[d0 + t];
        float sb = rb[0][t] + rb[1][t] + rb[2][t] + rb[3][t] + bb[d0 + t];
        float g = tanhf(sa) * (1.f / (1.f + expf(-sb)));
        float p = g * Wc[d0 + t];
        #pragma unroll
        for (int off = 32; off >= 1; off >>= 1) p += __shfl_down(p, off, 64);
        if (t == 0) {
            if (blockIdx.y == 0) p += bc[0];     // bias added exactly once
            atomicAdd(&a_logit[c], p);
        }
    }
}

__global__ __launch_bounds__(1024) void k_final(
    const float* __restrict__ hfc, const float* __restrict__ a_logit,
    const float* __restrict__ Wr, const float* __restrict__ br,
    const float* __restrict__ Wcls, const float* __restrict__ bcls,
    float* __restrict__ out)
{
    int t = threadIdx.x;
    __shared__ float hp[DH];
    __shared__ float r1[4][DATT];
    __shared__ float hr[DATT];
    __shared__ float wred[4][NCLS];

    float al[CNUM];
    float m = -1e30f;
    #pragma unroll
    for (int c = 0; c < CNUM; c++) { al[c] = a_logit[c]; m = fmaxf(m, al[c]); }
    float s = 0.f;
    #pragma unroll
    for (int c = 0; c < CNUM; c++) { al[c] = expf(al[c] - m); s += al[c]; }
    float inv = 1.f / s;

    if (t < DH) {
        float v = 0.f;
        #pragma unroll
        for (int c = 0; c < CNUM; c++) v = fmaf(al[c] * inv, hfc[c * DH + t], v);
        hp[t] = v;
    }
    __syncthreads();

    int d = t & 255;
    int ks = t >> 8;
    float acc = 0.f;
    #pragma unroll 8
    for (int k = ks * 128; k < ks * 128 + 128; k++)
        acc = fmaf(hp[k], Wr[(size_t)k * DATT + d], acc);
    r1[ks][d] = acc;
    __syncthreads();
    if (t < DATT)
        hr[t] = fmaxf(r1[0][t] + r1[1][t] + r1[2][t] + r1[3][t] + br[t], 0.f);
    __syncthreads();

    if (t < 256) {
        float h = hr[t];
        #pragma unroll
        for (int cls = 0; cls < NCLS; cls++) {
            float p = h * Wcls[(size_t)t * NCLS + cls];
            #pragma unroll
            for (int off = 32; off >= 1; off >>= 1) p += __shfl_down(p, off, 64);
            if ((t & 63) == 0) wred[t >> 6][cls] = p;
        }
    }
    __syncthreads();
    if (t == 0) {
        float lg[NCLS];
        #pragma unroll
        for (int cls = 0; cls < NCLS; cls++)
            lg[cls] = bcls[cls] + wred[0][cls] + wred[1][cls] + wred[2][cls] + wred[3][cls];
        float mm = lg[0];
        #pragma unroll
        for (int i = 1; i < NCLS; i++) mm = fmaxf(mm, lg[i]);
        float ss = 0.f, pr[NCLS];
        #pragma unroll
        for (int i = 0; i < NCLS; i++) { pr[i] = expf(lg[i] - mm); ss += pr[i]; }
        int am = 0; float best = lg[0];
        #pragma unroll
        for (int i = 1; i < NCLS; i++) if (lg[i] > best) { best = lg[i]; am = i; }
        #pragma unroll
        for (int i = 0; i < NCLS; i++) out[i] = lg[i];
        #pragma unroll
        for (int i = 0; i < NCLS; i++) out[4 + i] = pr[i] / ss;
        out[8] = (float)am;
    }
}

// ==================== FALLBACK PATH (small ws) — unchanged ====================

__global__ __launch_bounds__(256) void k_hist(
    const int* __restrict__ cid, int n, const float* __restrict__ bc,
    int* __restrict__ counts_part, float* __restrict__ pooled,
    float* __restrict__ a_logit, int* __restrict__ scat_pos)
{
    int bid = blockIdx.x;
    int t = threadIdx.x;

    if (bid < NH) {
        __shared__ int h[CNUM];
        int lane = t & 63;
        if (t < CNUM) h[t] = 0;
        __syncthreads();
        for (int i = bid * 256 + t; i < n; i += NH * 256) {
            int c = cid[i];
            #pragma unroll
            for (int cc = 0; cc < CNUM; cc++) {
                unsigned long long mask = __ballot(c == cc);
                if (mask == 0ull) continue;
                if (lane == (__ffsll(mask) - 1)) atomicAdd(&h[cc], __popcll(mask));
            }
        }
        __syncthreads();
        if (t < CNUM) counts_part[bid * 16 + t] = h[t];
        return;
    }

    for (int i = t; i < CNUM * DH; i += 256) pooled[i] = 0.f;
    if (t < CNUM) a_logit[t] = bc[0];
    if (t < CNUM) scat_pos[t] = 0;
}

__global__ __launch_bounds__(256) void k_scat_fb(
    const int* __restrict__ cid, int n, const int* __restrict__ counts_part,
    int* __restrict__ counts, int* __restrict__ offsets,
    int* __restrict__ scat_pos, int* __restrict__ bucket)
{
    int bid = blockIdx.x;
    int t = threadIdx.x;
    __shared__ int cnts[CNUM], off[CNUM];
    if (t < CNUM) {
        int s = 0;
        #pragma unroll 8
        for (int b = 0; b < NH; b++) s += counts_part[b * 16 + t];
        cnts[t] = s;
    }
    __syncthreads();
    if (t == 0) {
        int a = 0;
        for (int c = 0; c < CNUM; c++) { off[c] = a; a += cnts[c]; }
        if (bid == 0) {
            int aa = 0;
            for (int c = 0; c < CNUM; c++) { offsets[c] = aa; counts[c] = cnts[c]; aa += cnts[c]; }
            offsets[CNUM] = aa;
        }
    }
    __syncthreads();
    int lane = t & 63;
    for (int i = bid * 256 + t; i < n; i += NSC * 256) {
        int c = cid[i];
        #pragma unroll
        for (int cc = 0; cc < CNUM; cc++) {
            unsigned long long mask = __ballot(c == cc);
            if (mask == 0ull) continue;
            int leader = __ffsll(mask) - 1;
            int basep = 0;
            if (lane == leader) basep = atomicAdd(&scat_pos[cc], __popcll(mask));
            basep = __shfl(basep, leader, 64);
            if (c == cc) {
                int rank = __popcll(mask & ((1ull << lane) - 1ull));
                bucket[off[cc] + basep + rank] = i;
            }
        }
    }
}

__global__ __launch_bounds__(256) void k_gate2_fb(
    const float* __restrict__ hfc,
    const float* __restrict__ Wa, const float* __restrict__ ba,
    const float* __restrict__ Wb, const float* __restrict__ bb,
    const float* __restrict__ Wc,
    float* __restrict__ a_logit)
{
    int c = blockIdx.x;
    int d0 = blockIdx.y * 64;
    __shared__ float hf[DH];
    __shared__ float ra[4][64], rb[4][64];
    int t = threadIdx.x;
    hf[t] = hfc[c * DH + t];
    hf[t + 256] = hfc[c * DH + t + 256];
    __syncthreads();
    int d = d0 + (t & 63);
    int ks = t >> 6;
    float ga = 0.f, gb = 0.f;
    #pragma unroll 8
    for (int k = ks * 128; k < ks * 128 + 128; k++) {
        float h = hf[k];
        ga = fmaf(h, Wa[(size_t)k * DATT + d], ga);
        gb = fmaf(h, Wb[(size_t)k * DATT + d], gb);
    }
    ra[ks][t & 63] = ga;
    rb[ks][t & 63] = gb;
    __syncthreads();
    if (t < 64) {
        float sa = ra[0][t] + ra[1][t] + ra[2][t] + ra[3][t] + ba[d0 + t];
        float sb = rb[0][t] + rb[1][t] + rb[2][t] + rb[3][t] + bb[d0 + t];
        float g = tanhf(sa) * (1.f / (1.f + expf(-sb)));
        float p = g * Wc[d0 + t];
        #pragma unroll
        for (int off = 32; off >= 1; off >>= 1) p += __shfl_down(p, off, 64);
        if (t == 0) atomicAdd(&a_logit[c], p);
    }
}

#define MT 64
#define NT 128
#define KT 32

__global__ __launch_bounds__(256) void k_gemm1(
    const float* __restrict__ x, const float* __restrict__ W1, const float* __restrict__ b1,
    const int* __restrict__ bucket, const int* __restrict__ offsets, const int* __restrict__ counts,
    float* __restrict__ H1)
{
    int c = blockIdx.z;
    int cnt = counts[c];
    int m0 = blockIdx.x * MT;
    if (m0 >= cnt) return;
    int rows = min(MT, cnt - m0);
    int n0 = blockIdx.y * NT;
    int base = offsets[c];

    __shared__ float As[KT][MT + 4];
    __shared__ float Bs[KT][NT];

    int t = threadIdx.x;
    int tr = t >> 4;
    int tc = t & 15;
    int lr = t >> 2;
    int lk = (t & 3) * 8;
    const float* xrow = nullptr;
    if (lr < rows) xrow = x + (size_t)bucket[base + m0 + lr] * DIN;

    float acc[4][8];
    #pragma unroll
    for (int i = 0; i < 4; i++)
        #pragma unroll
        for (int j = 0; j < 8; j++) acc[i][j] = 0.f;

    const float* Wp = W1 + (size_t)c * DIN * DH + n0;

    for (int k0 = 0; k0 < DIN; k0 += KT) {
        __syncthreads();
        if (xrow) {
            float4 v0 = *(const float4*)(xrow + k0 + lk);
            float4 v1 = *(const float4*)(xrow + k0 + lk + 4);
            As[lk + 0][lr] = v0.x; As[lk + 1][lr] = v0.y;
            As[lk + 2][lr] = v0.z; As[lk + 3][lr] = v0.w;
            As[lk + 4][lr] = v1.x; As[lk + 5][lr] = v1.y;
            As[lk + 6][lr] = v1.z; As[lk + 7][lr] = v1.w;
        } else {
            #pragma unroll
            for (int i = 0; i < 8; i++) As[lk + i][lr] = 0.f;
        }
        #pragma unroll
        for (int i = 0; i < 4; i++) {
            int idx = i * 256 + t;
            int kk = idx >> 5;
            int cv = idx & 31;
            *(float4*)&Bs[kk][cv * 4] = *(const float4*)(Wp + (size_t)(k0 + kk) * DH + cv * 4);
        }
        __syncthreads();
        #pragma unroll
        for (int k = 0; k < KT; k++) {
            float4 av  = *(const float4*)&As[k][4 * tr];
            float4 bv0 = *(const float4*)&Bs[k][4 * tc];
            float4 bv1 = *(const float4*)&Bs[k][64 + 4 * tc];
            float a[4] = {av.x, av.y, av.z, av.w};
            float b[8] = {bv0.x, bv0.y, bv0.z, bv0.w, bv1.x, bv1.y, bv1.z, bv1.w};
            #pragma unroll
            for (int i = 0; i < 4; i++)
                #pragma unroll
                for (int j = 0; j < 8; j++)
                    acc[i][j] = fmaf(a[i], b[j], acc[i][j]);
        }
    }

    #pragma unroll
    for (int i = 0; i < 4; i++) {
        int r = 4 * tr + i;
        if (r < rows) {
            size_t grow = (size_t)(base + m0 + r) * DH;
            #pragma unroll
            for (int j = 0; j < 8; j++) {
                int cidx = (j < 4) ? (4 * tc + j) : (64 + 4 * tc + (j - 4));
                int col = n0 + cidx;
                float v = acc[i][j] + b1[c * DH + col];
                H1[grow + col] = fmaxf(v, 0.f);
            }
        }
    }
}

__global__ __launch_bounds__(256) void k_gemm2(
    const float* __restrict__ H1, const float* __restrict__ W2, const float* __restrict__ b2,
    const int* __restrict__ offsets, const int* __restrict__ counts,
    float* __restrict__ pooled)
{
    int c = blockIdx.z;
    int cnt = counts[c];
    int m0 = blockIdx.x * MT;
    if (m0 >= cnt) return;
    int rows = min(MT, cnt - m0);
    int n0 = blockIdx.y * NT;
    int base = offsets[c];

    __shared__ float As[KT][MT + 4];
    __shared__ float Bs[KT][NT];
    __shared__ float red[16][NT];

    int t = threadIdx.x;
    int tr = t >> 4;
    int tc = t & 15;
    int lr = t >> 2;
    int lk = (t & 3) * 8;
    const float* arow = (lr < rows) ? (H1 + (size_t)(base + m0 + lr) * DH) : nullptr;

    float acc[4][8];
    #pragma unroll
    for (int i = 0; i < 4; i++)
        #pragma unroll
        for (int j = 0; j < 8; j++) acc[i][j] = 0.f;

    const float* Wp = W2 + (size_t)c * DH * DH + n0;

    for (int k0 = 0; k0 < DH; k0 += KT) {
        __syncthreads();
        if (arow) {
            float4 v0 = *(const float4*)(arow + k0 + lk);
            float4 v1 = *(const float4*)(arow + k0 + lk + 4);
            As[lk + 0][lr] = v0.x; As[lk + 1][lr] = v0.y;
            As[lk + 2][lr] = v0.z; As[lk + 3][lr] = v0.w;
            As[lk + 4][lr] = v1.x; As[lk + 5][lr] = v1.y;
            As[lk + 6][lr] = v1.z; As[lk + 7][lr] = v1.w;
        } else {
            #pragma unroll
            for (int i = 0; i < 8; i++) As[lk + i][lr] = 0.f;
        }
        #pragma unroll
        for (int i = 0; i < 4; i++) {
            int idx = i * 256 + t;
            int kk = idx >> 5;
            int cv = idx & 31;
            *(float4*)&Bs[kk][cv * 4] = *(const float4*)(Wp + (size_t)(k0 + kk) * DH + cv * 4);
        }
        __syncthreads();
        #pragma unroll
        for (int k = 0; k < KT; k++) {
            float4 av  = *(const float4*)&As[k][4 * tr];
            float4 bv0 = *(const float4*)&Bs[k][4 * tc];
            float4 bv1 = *(const float4*)&Bs[k][64 + 4 * tc];
            float a[4] = {av.x, av.y, av.z, av.w};
            float b[8] = {bv0.x, bv0.y, bv0.z, bv0.w, bv1.x, bv1.y, bv1.z, bv1.w};
            #pragma unroll
            for (int i = 0; i < 4; i++)
                #pragma unroll
                for (int j = 0; j < 8; j++)
                    acc[i][j] = fmaf(a[i], b[j], acc[i][j]);
        }
    }

    __syncthreads();
    #pragma unroll
    for (int j = 0; j < 8; j++) {
        int cidx = (j < 4) ? (4 * tc + j) : (64 + 4 * tc + (j - 4));
        float bias = b2[c * DH + n0 + cidx];
        float s = 0.f;
        #pragma unroll
        for (int i = 0; i < 4; i++) {
            if (4 * tr + i < rows) s += fmaxf(acc[i][j] + bias, 0.f);
        }
        red[tr][cidx] = s;
    }
    __syncthreads();
    if (t < NT) {
        float s = 0.f;
        #pragma unroll
        for (int r = 0; r < 16; r++) s += red[r][t];
        atomicAdd(&pooled[c * DH + n0 + t], s);
    }
}

// ---------------- launcher ----------------

extern "C" void kernel_launch(void* const* d_in, const int* in_sizes, int n_in,
                              void* d_out, int out_size, void* d_ws, size_t ws_size,
                              hipStream_t stream) {
    (void)n_in; (void)out_size;
    const float* x    = (const float*)d_in[0];
    const int*   cid  = (const int*)d_in[1];
    const float* W1   = (const float*)d_in[2];
    const float* b1   = (const float*)d_in[3];
    const float* W2   = (const float*)d_in[4];
    const float* b2   = (const float*)d_in[5];
    const float* Wfc  = (const float*)d_in[6];
    const float* bfc  = (const float*)d_in[7];
    const float* Wa   = (const float*)d_in[8];
    const float* ba   = (const float*)d_in[9];
    const float* Wb   = (const float*)d_in[10];
    const float* bb   = (const float*)d_in[11];
    const float* Wc   = (const float*)d_in[12];
    const float* bc   = (const float*)d_in[13];
    const float* Wr   = (const float*)d_in[14];
    const float* br   = (const float*)d_in[15];
    const float* Wcls = (const float*)d_in[16];
    const float* bcls = (const float*)d_in[17];
    float* out = (float*)d_out;
    float* ws  = (float*)d_ws;

    int n = in_sizes[1];

    // ---- fast layout ----
    float* pooled   = ws;                          // 5120 f
    int*   scat_pos = (int*)(ws + 5120);           // 16 i (doubles as counts)
    float* a_logit  = ws + 5136;                   // 16 f  (zeroed by memset)
    float* hfc      = ws + 5152;                   // 5120 f -> 10272
    int*   bucket   = (int*)(ws + 10272);          // CNUM * n (padded per-cluster)

    size_t big0 = (((size_t)(10272 + (size_t)CNUM * n) * 4) + 255) & ~(size_t)255;
    size_t w1t_bytes = (size_t)CNUM * DH * DIN * 2;
    size_t w2t_bytes = (size_t)CNUM * DH * DH * 2;
    size_t h1_bytes  = (size_t)(n + 64 * CNUM) * DH * 2;   // compact 64-padded rows
    size_t need = big0 + w1t_bytes + w2t_bytes + h1_bytes;

    if (ws_size >= need) {
        ushort_t* W1t = (ushort_t*)((char*)d_ws + big0);
        ushort_t* W2t = (ushort_t*)((char*)d_ws + big0 + w1t_bytes);
        ushort_t* H1  = (ushort_t*)((char*)d_ws + big0 + w1t_bytes + w2t_bytes);

        int nw  = 128 * 2 * CNUM;
        // 64-row m-tiles: sum ceil(cnt/64) <= n/64 + CNUM; round up to mult of 8
        int MAXT = ((n / 64 + CNUM + 1) + 7) & ~7;

        hipMemsetAsync(ws, 0, 5152 * 4, stream);   // pooled + scat_pos + a_logit
        k_prep<<<NSC + nw, 256, 0, stream>>>(cid, n, W1, W2, W1t, W2t, nw, scat_pos, bucket);
        k_g1<<<8 * MAXT, 256, 0, stream>>>(x, W1t, b1, bucket, scat_pos, n, MAXT, H1);
        k_g2<<<8 * MAXT, 256, 0, stream>>>(H1, W2t, b2, scat_pos, n, MAXT, pooled);
        k_fc2<<<dim3(CNUM, 8), 256, 0, stream>>>(pooled, scat_pos, Wfc, bfc, hfc);
        k_gate2<<<dim3(CNUM, 4), 256, 0, stream>>>(hfc, Wa, ba, Wb, bb, Wc, bc, a_logit);
        k_final<<<1, 1024, 0, stream>>>(hfc, a_logit, Wr, br, Wcls, bcls, out);
    } else {
        // ---- fallback: old fp32 pipeline, old layout ----
        float* pooledF     = ws + 0;
        int*   countsF     = (int*)(ws + 5120);
        int*   offsetsF    = (int*)(ws + 5136);
        float* a_logitF    = ws + 5168;
        int*   scat_posF   = (int*)(ws + 5184);
        float* hfcF        = ws + 5200;
        int*   counts_part = (int*)(ws + 10320);
        int*   bucketF     = (int*)(ws + 11344);

        k_hist<<<NH + 1, 256, 0, stream>>>(cid, n, bc, counts_part, pooledF, a_logitF, scat_posF);
        k_scat_fb<<<NSC, 256, 0, stream>>>(cid, n, counts_part, countsF, offsetsF, scat_posF, bucketF);

        float* H1f = ws + ((11344 + n + 31) & ~31);
        dim3 gg((n + MT - 1) / MT, DH / NT, CNUM);
        k_gemm1<<<gg, 256, 0, stream>>>(x, W1, b1, bucketF, offsetsF, countsF, H1f);
        k_gemm2<<<gg, 256, 0, stream>>>(H1f, W2, b2, offsetsF, countsF, pooledF);

        k_fc2<<<dim3(CNUM, 8), 256, 0, stream>>>(pooledF, countsF, Wfc, bfc, hfcF);
        k_gate2_fb<<<dim3(CNUM, 4), 256, 0, stream>>>(hfcF, Wa, ba, Wb, bb, Wc, a_logitF);
        k_final<<<1, 1024, 0, stream>>>(hfcF, a_logitF, Wr, br, Wcls, bcls, out);
    }
}

// Round 5
// 219.815 us; speedup vs baseline: 1.2944x; 1.0904x over previous
//
#include <hip/hip_runtime.h>
#include <math.h>

#define DIN 1024
#define DH 512
#define DATT 256
#define CNUM 10
#define NCLS 4
#define NH 64              // histogram blocks (fallback path)
#define NSC 40             // scatter blocks

typedef __attribute__((ext_vector_type(8))) short bf16x8;
typedef __attribute__((ext_vector_type(4))) float f32x4;
typedef unsigned short ushort_t;
typedef unsigned int uint_t;

__device__ inline ushort_t f2bf(float f) {
    uint_t u = __float_as_uint(f);
    u += 0x7FFF + ((u >> 16) & 1);   // RNE
    return (ushort_t)(u >> 16);
}

// async global->LDS, 16B per lane. LDS dst must be wave-uniform base + lane*16.
__device__ inline void gl_lds16(const void* g, void* l) {
    __builtin_amdgcn_global_load_lds(
        (const __attribute__((address_space(1))) unsigned int*)g,
        (__attribute__((address_space(3))) unsigned int*)l, 16, 0, 0);
}

// ============================ FAST PATH ============================
// dispatch 1: memset (pooled + scat_pos + a_logit)
// dispatch 2: k_prep  = scatter | x cast | W transpose+cast
// dispatch 3: k_g1    = grouped GEMM1, 64x64 tile, BK=64, RING-3 2-deep prefetch
// dispatch 4: k_g2    = grouped GEMM2 + relu colsum -> pooled (same ring)
// dispatch 5-7: k_fc2 / k_gate2 / k_final

__global__ __launch_bounds__(256) void k_prep(
    const int* __restrict__ cid, int n,
    const float* __restrict__ x, const float* __restrict__ W1, const float* __restrict__ W2,
    ushort_t* __restrict__ xb, ushort_t* __restrict__ W1t, ushort_t* __restrict__ W2t,
    int nxb, int nw,
    int* __restrict__ scat_pos, int* __restrict__ bucket)
{
    int bid = blockIdx.x;
    int t = threadIdx.x;

    if (bid < NSC) {                      // direct-atomic scatter into padded buckets
        int lane = t & 63;
        for (int i = bid * 256 + t; i < n; i += NSC * 256) {
            int c = cid[i];
            #pragma unroll
            for (int cc = 0; cc < CNUM; cc++) {
                unsigned long long mask = __ballot(c == cc);
                if (mask == 0ull) continue;
                int leader = __ffsll(mask) - 1;
                int basep = 0;
                if (lane == leader) basep = atomicAdd(&scat_pos[cc], __popcll(mask));
                basep = __shfl(basep, leader, 64);
                if (c == cc) {
                    int rank = __popcll(mask & ((1ull << lane) - 1ull));
                    bucket[cc * n + basep + rank] = i;
                }
            }
        }
        return;
    }
    bid -= NSC;

    if (bid < nxb) {                      // cast x fp32 -> bf16, 4 rows/block
        int row = bid * 4 + (t >> 6);
        if (row >= n) return;
        int col = (t & 63) * 16;
        const float* src = x + (size_t)row * DIN + col;
        ushort_t* dst = xb + (size_t)row * DIN + col;
        #pragma unroll
        for (int j = 0; j < 4; j++) {
            float4 v = *(const float4*)(src + 4 * j);
            *(ushort4*)(dst + 4 * j) = make_ushort4(f2bf(v.x), f2bf(v.y), f2bf(v.z), f2bf(v.w));
        }
        return;
    }
    bid -= nxb;

    if (bid < nw) {                       // transpose+cast W1,W2 -> n-major bf16
        __shared__ float tile[64][65];
        int z = bid >> 7;
        int kx = (bid & 127) >> 3;
        int ny = bid & 7;
        const float* src; ushort_t* dst; int K;
        if (z < CNUM) { K = DIN; src = W1 + (size_t)z * K * DH; dst = W1t + (size_t)z * DH * K; }
        else          { K = DH;  src = W2 + (size_t)(z - CNUM) * K * DH; dst = W2t + (size_t)(z - CNUM) * DH * K; }
        int k0 = kx * 64;
        if (k0 >= K) return;
        int n0 = ny * 64;
        int rr = t >> 4;
        int cc = (t & 15) * 4;
        #pragma unroll
        for (int i = 0; i < 4; i++) {
            int row = rr + 16 * i;
            float4 v = *(const float4*)(src + (size_t)(k0 + row) * DH + n0 + cc);
            tile[row][cc + 0] = v.x; tile[row][cc + 1] = v.y;
            tile[row][cc + 2] = v.z; tile[row][cc + 3] = v.w;
        }
        __syncthreads();
        #pragma unroll
        for (int i = 0; i < 4; i++) {
            int nrow = rr + 16 * i;
            ushort4 o = make_ushort4(f2bf(tile[cc + 0][nrow]), f2bf(tile[cc + 1][nrow]),
                                     f2bf(tile[cc + 2][nrow]), f2bf(tile[cc + 3][nrow]));
            *(ushort4*)(dst + (size_t)(n0 + nrow) * K + k0 + cc) = o;
        }
    }
}

// ------- 64x64 tile, BK=64, RING-3 double-deep prefetch (T3+T4, T2 swizzle) -------
// Per K-tile each wave issues 4 gl_lds (1 KB each). Steady state keeps 2 tiles
// (8 ops/wave) in flight: vmcnt(8) retires tile kt while kt+1, kt+2 fly ->
// one HBM latency (~900cy) spans TWO steps of ds_read+MFMA+barrier work.
// XOR chunk swizzle: 16B-chunk index ^= (row&7); pre-swizzled global source,
// linear LDS dst, identical XOR on the ds_read side (both-sides rule).

__device__ inline void stage4(
    const ushort_t* a0, const ushort_t* a1,
    const ushort_t* b0, const ushort_t* b1,
    int ko, ushort_t* As, ushort_t* Bs, int t)
{
    gl_lds16(a0 + ko, As + 0 * 2048 + t * 8);
    gl_lds16(a1 + ko, As + 1 * 2048 + t * 8);
    gl_lds16(b0 + ko, Bs + 0 * 2048 + t * 8);
    gl_lds16(b1 + ko, Bs + 1 * 2048 + t * 8);
}

__device__ inline void gemm_ring(
    const ushort_t* a0, const ushort_t* a1,
    const ushort_t* b0, const ushort_t* b1,
    int KT, f32x4 (&acc)[2][2], ushort_t* As, ushort_t* Bs)
{
    int t = threadIdx.x;
    int lane = t & 63;
    int w = t >> 6, wr = w >> 1, wc = w & 1;
    int m = lane & 15, quad = lane >> 4;

    stage4(a0, a1, b0, b1, 0,  As,        Bs,        t);   // tile 0 -> buf0
    stage4(a0, a1, b0, b1, 64, As + 4096, Bs + 4096, t);   // tile 1 -> buf1

    int buf = 0;
    for (int kt = 0; kt < KT; kt++) {
        // issue tile kt+2 into the buffer consumed at iter kt-1 (safe: all waves
        // crossed the post-read barrier of kt-1 before reaching this point)
        if (kt + 2 < KT) {
            int nb = buf + 2; if (nb >= 3) nb -= 3;
            stage4(a0, a1, b0, b1, (kt + 2) * 64, As + nb * 4096, Bs + nb * 4096, t);
            asm volatile("s_waitcnt vmcnt(8)" ::: "memory");   // tile kt resident
        } else if (kt + 1 < KT) {
            asm volatile("s_waitcnt vmcnt(4)" ::: "memory");
        } else {
            asm volatile("s_waitcnt vmcnt(0)" ::: "memory");
        }
        __builtin_amdgcn_sched_barrier(0);
        __builtin_amdgcn_s_barrier();                          // tile kt published
        __builtin_amdgcn_sched_barrier(0);

        const ushort_t* Ab = As + buf * 4096;
        const ushort_t* Bb = Bs + buf * 4096;
        bf16x8 a[2][2], b[2][2];
        #pragma unroll
        for (int ks = 0; ks < 2; ks++) {
            int chunk = ((ks * 4 + quad) ^ (m & 7)) * 8;       // row&7 == m&7
            #pragma unroll
            for (int mf = 0; mf < 2; mf++)
                a[ks][mf] = *(const bf16x8*)(Ab + (32 * wr + 16 * mf + m) * 64 + chunk);
            #pragma unroll
            for (int nf = 0; nf < 2; nf++)
                b[ks][nf] = *(const bf16x8*)(Bb + (32 * wc + 16 * nf + m) * 64 + chunk);
        }
        asm volatile("s_waitcnt lgkmcnt(0)" ::: "memory");     // own reads complete
        __builtin_amdgcn_sched_barrier(0);
        __builtin_amdgcn_s_barrier();                          // all reads of buf done
        __builtin_amdgcn_sched_barrier(0);

        #pragma unroll
        for (int ks = 0; ks < 2; ks++)
            #pragma unroll
            for (int mf = 0; mf < 2; mf++)
                #pragma unroll
                for (int nf = 0; nf < 2; nf++)
                    acc[mf][nf] = __builtin_amdgcn_mfma_f32_16x16x32_bf16(a[ks][mf], b[ks][nf], acc[mf][nf], 0, 0, 0);

        buf = buf + 1; if (buf == 3) buf = 0;
    }
}

// tile mapping: bijective XCD remap (T1) then counts-prefix -> (cluster, m0, H1 base).
// 64-row m-tiles, 64-col n-tiles (NTILES = DH/64 = 8). H1 rows are 64-padded
// per cluster: base(c) = sum_{cc<c} ceil(counts[cc]/64)*64  (compact, ~10.6 MB).
__device__ inline int tile_decode(int bid, int MAXT, const int* counts,
                                  int& c, int& m0, int& tile_n, int& base)
{
    int mt, nt;
    if ((MAXT & 7) == 0) {
        int mtpx = MAXT >> 3;
        int xcd = bid & 7, j = bid >> 3;
        nt = j / mtpx;                       // all n-tiles of an m-chunk on one XCD
        mt = xcd * mtpx + (j - nt * mtpx);
    } else { mt = bid >> 3; nt = bid & 7; }

    int rem = mt;
    c = 0; base = 0;
    #pragma unroll
    for (int cc = 0; cc < CNUM; cc++) {
        int tc = (counts[cc] + 63) >> 6;
        if (rem < tc) { c = cc; m0 = rem * 64; tile_n = nt * 64; return 1; }
        rem -= tc;
        base += tc * 64;
    }
    return 0;
}

__global__ __launch_bounds__(256, 3) void k_g1(
    const ushort_t* __restrict__ xb, const ushort_t* __restrict__ W1t,
    const float* __restrict__ b1, const int* __restrict__ bucket,
    const int* __restrict__ counts, int n, int MAXT,
    ushort_t* __restrict__ H1)
{
    __shared__ ushort_t As[3][64][64];
    __shared__ ushort_t Bs[3][64][64];

    int c, m0, tile_n, base;
    if (!tile_decode(blockIdx.x, MAXT, counts, c, m0, tile_n, base)) return;
    int cnt = counts[c];

    int t = threadIdx.x;
    int rr = t >> 3;                                   // row within 32-row plane
    int swz = ((t & 7) ^ (rr & 7)) * 8;                // pre-swizzled global chunk

    const ushort_t* aP[2];
    const ushort_t* bP[2];
    #pragma unroll
    for (int s = 0; s < 2; s++) {
        int ra = m0 + s * 32 + rr;
        if (ra > cnt - 1) ra = cnt - 1;
        if (ra < 0) ra = 0;
        aP[s] = xb + (size_t)bucket[c * n + ra] * DIN + swz;            // indirect gather
        bP[s] = W1t + ((size_t)c * DH + tile_n + s * 32 + rr) * DIN + swz;
    }

    f32x4 acc[2][2] = {};
    gemm_ring(aP[0], aP[1], bP[0], bP[1], DIN / 64, acc, &As[0][0][0], &Bs[0][0][0]);

    int lane = t & 63;
    int w = t >> 6, wr = w >> 1, wc = w & 1;
    int m = lane & 15, quad = lane >> 4;
    int col0 = tile_n + 32 * wc;
    #pragma unroll
    for (int nf = 0; nf < 2; nf++) {
        int col = col0 + 16 * nf + m;
        float bv = b1[c * DH + col];
        #pragma unroll
        for (int mf = 0; mf < 2; mf++) {
            int rowb = m0 + 32 * wr + 16 * mf + quad * 4;
            #pragma unroll
            for (int r = 0; r < 4; r++) {
                int row = rowb + r;
                if (row < cnt)
                    H1[(size_t)(base + row) * DH + col] = f2bf(fmaxf(acc[mf][nf][r] + bv, 0.f));
            }
        }
    }
}

__global__ __launch_bounds__(256, 3) void k_g2(
    const ushort_t* __restrict__ H1, const ushort_t* __restrict__ W2t,
    const float* __restrict__ b2, const int* __restrict__ counts, int n, int MAXT,
    float* __restrict__ pooled)
{
    __shared__ ushort_t As[3][64][64];
    __shared__ ushort_t Bs[3][64][64];

    int c, m0, tile_n, base;
    if (!tile_decode(blockIdx.x, MAXT, counts, c, m0, tile_n, base)) return;
    int cnt = counts[c];

    int t = threadIdx.x;
    int rr = t >> 3;
    int swz = ((t & 7) ^ (rr & 7)) * 8;

    const ushort_t* aP[2];
    const ushort_t* bP[2];
    #pragma unroll
    for (int s = 0; s < 2; s++) {
        int ra = m0 + s * 32 + rr;
        if (ra > cnt - 1) ra = cnt - 1;
        if (ra < 0) ra = 0;
        aP[s] = H1 + (size_t)(base + ra) * DH + swz;
        bP[s] = W2t + ((size_t)c * DH + tile_n + s * 32 + rr) * DH + swz;
    }

    f32x4 acc[2][2] = {};
    gemm_ring(aP[0], aP[1], bP[0], bP[1], DH / 64, acc, &As[0][0][0], &Bs[0][0][0]);

    int lane = t & 63;
    int w = t >> 6, wr = w >> 1, wc = w & 1;
    int m = lane & 15, quad = lane >> 4;
    int col0 = tile_n + 32 * wc;
    #pragma unroll
    for (int nf = 0; nf < 2; nf++) {
        int col = col0 + 16 * nf + m;
        float bv = b2[c * DH + col];
        float s = 0.f;
        #pragma unroll
        for (int mf = 0; mf < 2; mf++) {
            int rowb = m0 + 32 * wr + 16 * mf + quad * 4;
            #pragma unroll
            for (int r = 0; r < 4; r++) {
                int row = rowb + r;
                if (row < cnt) s += fmaxf(acc[mf][nf][r] + bv, 0.f);
            }
        }
        s += __shfl_xor(s, 16);
        s += __shfl_xor(s, 32);
        if (quad == 0) atomicAdd(&pooled[c * DH + col], s);
    }
}

// ---------------- parallel epilogue (80/40/1 blocks — R3 lesson) ----------------

__global__ __launch_bounds__(256) void k_fc2(
    const float* __restrict__ pooled, const int* __restrict__ counts,
    const float* __restrict__ Wfc, const float* __restrict__ bfc,
    float* __restrict__ hfc)
{
    int c = blockIdx.x;
    int c0 = blockIdx.y * 64;
    __shared__ float ps[DH];
    __shared__ float red[4][64];
    int t = threadIdx.x;
    float cnt = fmaxf((float)counts[c], 1.f);
    ps[t] = pooled[c * DH + t] / cnt;
    ps[t + 256] = pooled[c * DH + t + 256] / cnt;
    __syncthreads();
    int col = c0 + (t & 63);
    int ks = t >> 6;
    float acc = 0.f;
    #pragma unroll 8
    for (int k = ks * 128; k < ks * 128 + 128; k++)
        acc = fmaf(ps[k], Wfc[(size_t)k * DH + col], acc);
    red[ks][t & 63] = acc;
    __syncthreads();
    if (t < 64) {
        float v = red[0][t] + red[1][t] + red[2][t] + red[3][t] + bfc[c0 + t];
        hfc[c * DH + c0 + t] = fmaxf(v, 0.f);
    }
}

__global__ __launch_bounds__(256) void k_gate2(
    const float* __restrict__ hfc,
    const float* __restrict__ Wa, const float* __restrict__ ba,
    const float* __restrict__ Wb, const float* __restrict__ bb,
    const float* __restrict__ Wc, const float* __restrict__ bc,
    float* __restrict__ a_logit)
{
    int c = blockIdx.x;
    int d0 = blockIdx.y * 64;
    __shared__ float hf[DH];
    __shared__ float ra[4][64], rb[4][64];
    int t = threadIdx.x;
    hf[t] = hfc[c * DH + t];
    hf[t + 256] = hfc[c * DH + t + 256];
    __syncthreads();
    int d = d0 + (t & 63);
    int ks = t >> 6;
    float ga = 0.f, gb = 0.f;
    #pragma unroll 8
    for (int k = ks * 128; k < ks * 128 + 128; k++) {
        float h = hf[k];
        ga = fmaf(h, Wa[(size_t)k * DATT + d], ga);
        gb = fmaf(h, Wb[(size_t)k * DATT + d], gb);
    }
    ra[ks][t & 63] = ga;
    rb[ks][t & 63] = gb;
    __syncthreads();
    if (t < 64) {
        float sa = ra[0][t] + ra[1][t] + ra[2][t] + ra[3][t] + ba[d0 + t];
        float sb = rb[0][t] + rb[1][t] + rb[2][t] + rb[3][t] + bb[d0 + t];
        float g = tanhf(sa) * (1.f / (1.f + expf(-sb)));
        float p = g * Wc[d0 + t];
        #pragma unroll
        for (int off = 32; off >= 1; off >>= 1) p += __shfl_down(p, off, 64);
        if (t == 0) {
            if (blockIdx.y == 0) p += bc[0];     // bias added exactly once
            atomicAdd(&a_logit[c], p);
        }
    }
}

__global__ __launch_bounds__(1024) void k_final(
    const float* __restrict__ hfc, const float* __restrict__ a_logit,
    const float* __restrict__ Wr, const float* __restrict__ br,
    const float* __restrict__ Wcls, const float* __restrict__ bcls,
    float* __restrict__ out)
{
    int t = threadIdx.x;
    __shared__ float hp[DH];
    __shared__ float r1[4][DATT];
    __shared__ float hr[DATT];
    __shared__ float wred[4][NCLS];

    float al[CNUM];
    float m = -1e30f;
    #pragma unroll
    for (int c = 0; c < CNUM; c++) { al[c] = a_logit[c]; m = fmaxf(m, al[c]); }
    float s = 0.f;
    #pragma unroll
    for (int c = 0; c < CNUM; c++) { al[c] = expf(al[c] - m); s += al[c]; }
    float inv = 1.f / s;

    if (t < DH) {
        float v = 0.f;
        #pragma unroll
        for (int c = 0; c < CNUM; c++) v = fmaf(al[c] * inv, hfc[c * DH + t], v);
        hp[t] = v;
    }
    __syncthreads();

    int d = t & 255;
    int ks = t >> 8;
    float acc = 0.f;
    #pragma unroll 8
    for (int k = ks * 128; k < ks * 128 + 128; k++)
        acc = fmaf(hp[k], Wr[(size_t)k * DATT + d], acc);
    r1[ks][d] = acc;
    __syncthreads();
    if (t < DATT)
        hr[t] = fmaxf(r1[0][t] + r1[1][t] + r1[2][t] + r1[3][t] + br[t], 0.f);
    __syncthreads();

    if (t < 256) {
        float h = hr[t];
        #pragma unroll
        for (int cls = 0; cls < NCLS; cls++) {
            float p = h * Wcls[(size_t)t * NCLS + cls];
            #pragma unroll
            for (int off = 32; off >= 1; off >>= 1) p += __shfl_down(p, off, 64);
            if ((t & 63) == 0) wred[t >> 6][cls] = p;
        }
    }
    __syncthreads();
    if (t == 0) {
        float lg[NCLS];
        #pragma unroll
        for (int cls = 0; cls < NCLS; cls++)
            lg[cls] = bcls[cls] + wred[0][cls] + wred[1][cls] + wred[2][cls] + wred[3][cls];
        float mm = lg[0];
        #pragma unroll
        for (int i = 1; i < NCLS; i++) mm = fmaxf(mm, lg[i]);
        float ss = 0.f, pr[NCLS];
        #pragma unroll
        for (int i = 0; i < NCLS; i++) { pr[i] = expf(lg[i] - mm); ss += pr[i]; }
        int am = 0; float best = lg[0];
        #pragma unroll
        for (int i = 1; i < NCLS; i++) if (lg[i] > best) { best = lg[i]; am = i; }
        #pragma unroll
        for (int i = 0; i < NCLS; i++) out[i] = lg[i];
        #pragma unroll
        for (int i = 0; i < NCLS; i++) out[4 + i] = pr[i] / ss;
        out[8] = (float)am;
    }
}

// ==================== FALLBACK PATH (small ws) — unchanged ====================

__global__ __launch_bounds__(256) void k_hist(
    const int* __restrict__ cid, int n, const float* __restrict__ bc,
    int* __restrict__ counts_part, float* __restrict__ pooled,
    float* __restrict__ a_logit, int* __restrict__ scat_pos)
{
    int bid = blockIdx.x;
    int t = threadIdx.x;

    if (bid < NH) {
        __shared__ int h[CNUM];
        int lane = t & 63;
        if (t < CNUM) h[t] = 0;
        __syncthreads();
        for (int i = bid * 256 + t; i < n; i += NH * 256) {
            int c = cid[i];
            #pragma unroll
            for (int cc = 0; cc < CNUM; cc++) {
                unsigned long long mask = __ballot(c == cc);
                if (mask == 0ull) continue;
                if (lane == (__ffsll(mask) - 1)) atomicAdd(&h[cc], __popcll(mask));
            }
        }
        __syncthreads();
        if (t < CNUM) counts_part[bid * 16 + t] = h[t];
        return;
    }

    for (int i = t; i < CNUM * DH; i += 256) pooled[i] = 0.f;
    if (t < CNUM) a_logit[t] = bc[0];
    if (t < CNUM) scat_pos[t] = 0;
}

__global__ __launch_bounds__(256) void k_scat_fb(
    const int* __restrict__ cid, int n, const int* __restrict__ counts_part,
    int* __restrict__ counts, int* __restrict__ offsets,
    int* __restrict__ scat_pos, int* __restrict__ bucket)
{
    int bid = blockIdx.x;
    int t = threadIdx.x;
    __shared__ int cnts[CNUM], off[CNUM];
    if (t < CNUM) {
        int s = 0;
        #pragma unroll 8
        for (int b = 0; b < NH; b++) s += counts_part[b * 16 + t];
        cnts[t] = s;
    }
    __syncthreads();
    if (t == 0) {
        int a = 0;
        for (int c = 0; c < CNUM; c++) { off[c] = a; a += cnts[c]; }
        if (bid == 0) {
            int aa = 0;
            for (int c = 0; c < CNUM; c++) { offsets[c] = aa; counts[c] = cnts[c]; aa += cnts[c]; }
            offsets[CNUM] = aa;
        }
    }
    __syncthreads();
    int lane = t & 63;
    for (int i = bid * 256 + t; i < n; i += NSC * 256) {
        int c = cid[i];
        #pragma unroll
        for (int cc = 0; cc < CNUM; cc++) {
            unsigned long long mask = __ballot(c == cc);
            if (mask == 0ull) continue;
            int leader = __ffsll(mask) - 1;
            int basep = 0;
            if (lane == leader) basep = atomicAdd(&scat_pos[cc], __popcll(mask));
            basep = __shfl(basep, leader, 64);
            if (c == cc) {
                int rank = __popcll(mask & ((1ull << lane) - 1ull));
                bucket[off[cc] + basep + rank] = i;
            }
        }
    }
}

__global__ __launch_bounds__(256) void k_gate2_fb(
    const float* __restrict__ hfc,
    const float* __restrict__ Wa, const float* __restrict__ ba,
    const float* __restrict__ Wb, const float* __restrict__ bb,
    const float* __restrict__ Wc,
    float* __restrict__ a_logit)
{
    int c = blockIdx.x;
    int d0 = blockIdx.y * 64;
    __shared__ float hf[DH];
    __shared__ float ra[4][64], rb[4][64];
    int t = threadIdx.x;
    hf[t] = hfc[c * DH + t];
    hf[t + 256] = hfc[c * DH + t + 256];
    __syncthreads();
    int d = d0 + (t & 63);
    int ks = t >> 6;
    float ga = 0.f, gb = 0.f;
    #pragma unroll 8
    for (int k = ks * 128; k < ks * 128 + 128; k++) {
        float h = hf[k];
        ga = fmaf(h, Wa[(size_t)k * DATT + d], ga);
        gb = fmaf(h, Wb[(size_t)k * DATT + d], gb);
    }
    ra[ks][t & 63] = ga;
    rb[ks][t & 63] = gb;
    __syncthreads();
    if (t < 64) {
        float sa = ra[0][t] + ra[1][t] + ra[2][t] + ra[3][t] + ba[d0 + t];
        float sb = rb[0][t] + rb[1][t] + rb[2][t] + rb[3][t] + bb[d0 + t];
        float g = tanhf(sa) * (1.f / (1.f + expf(-sb)));
        float p = g * Wc[d0 + t];
        #pragma unroll
        for (int off = 32; off >= 1; off >>= 1) p += __shfl_down(p, off, 64);
        if (t == 0) atomicAdd(&a_logit[c], p);
    }
}

#define MT 64
#define NT 128
#define KT 32

__global__ __launch_bounds__(256) void k_gemm1(
    const float* __restrict__ x, const float* __restrict__ W1, const float* __restrict__ b1,
    const int* __restrict__ bucket, const int* __restrict__ offsets, const int* __restrict__ counts,
    float* __restrict__ H1)
{
    int c = blockIdx.z;
    int cnt = counts[c];
    int m0 = blockIdx.x * MT;
    if (m0 >= cnt) return;
    int rows = min(MT, cnt - m0);
    int n0 = blockIdx.y * NT;
    int base = offsets[c];

    __shared__ float As[KT][MT + 4];
    __shared__ float Bs[KT][NT];

    int t = threadIdx.x;
    int tr = t >> 4;
    int tc = t & 15;
    int lr = t >> 2;
    int lk = (t & 3) * 8;
    const float* xrow = nullptr;
    if (lr < rows) xrow = x + (size_t)bucket[base + m0 + lr] * DIN;

    float acc[4][8];
    #pragma unroll
    for (int i = 0; i < 4; i++)
        #pragma unroll
        for (int j = 0; j < 8; j++) acc[i][j] = 0.f;

    const float* Wp = W1 + (size_t)c * DIN * DH + n0;

    for (int k0 = 0; k0 < DIN; k0 += KT) {
        __syncthreads();
        if (xrow) {
            float4 v0 = *(const float4*)(xrow + k0 + lk);
            float4 v1 = *(const float4*)(xrow + k0 + lk + 4);
            As[lk + 0][lr] = v0.x; As[lk + 1][lr] = v0.y;
            As[lk + 2][lr] = v0.z; As[lk + 3][lr] = v0.w;
            As[lk + 4][lr] = v1.x; As[lk + 5][lr] = v1.y;
            As[lk + 6][lr] = v1.z; As[lk + 7][lr] = v1.w;
        } else {
            #pragma unroll
            for (int i = 0; i < 8; i++) As[lk + i][lr] = 0.f;
        }
        #pragma unroll
        for (int i = 0; i < 4; i++) {
            int idx = i * 256 + t;
            int kk = idx >> 5;
            int cv = idx & 31;
            *(float4*)&Bs[kk][cv * 4] = *(const float4*)(Wp + (size_t)(k0 + kk) * DH + cv * 4);
        }
        __syncthreads();
        #pragma unroll
        for (int k = 0; k < KT; k++) {
            float4 av  = *(const float4*)&As[k][4 * tr];
            float4 bv0 = *(const float4*)&Bs[k][4 * tc];
            float4 bv1 = *(const float4*)&Bs[k][64 + 4 * tc];
            float a[4] = {av.x, av.y, av.z, av.w};
            float b[8] = {bv0.x, bv0.y, bv0.z, bv0.w, bv1.x, bv1.y, bv1.z, bv1.w};
            #pragma unroll
            for (int i = 0; i < 4; i++)
                #pragma unroll
                for (int j = 0; j < 8; j++)
                    acc[i][j] = fmaf(a[i], b[j], acc[i][j]);
        }
    }

    #pragma unroll
    for (int i = 0; i < 4; i++) {
        int r = 4 * tr + i;
        if (r < rows) {
            size_t grow = (size_t)(base + m0 + r) * DH;
            #pragma unroll
            for (int j = 0; j < 8; j++) {
                int cidx = (j < 4) ? (4 * tc + j) : (64 + 4 * tc + (j - 4));
                int col = n0 + cidx;
                float v = acc[i][j] + b1[c * DH + col];
                H1[grow + col] = fmaxf(v, 0.f);
            }
        }
    }
}

__global__ __launch_bounds__(256) void k_gemm2(
    const float* __restrict__ H1, const float* __restrict__ W2, const float* __restrict__ b2,
    const int* __restrict__ offsets, const int* __restrict__ counts,
    float* __restrict__ pooled)
{
    int c = blockIdx.z;
    int cnt = counts[c];
    int m0 = blockIdx.x * MT;
    if (m0 >= cnt) return;
    int rows = min(MT, cnt - m0);
    int n0 = blockIdx.y * NT;
    int base = offsets[c];

    __shared__ float As[KT][MT + 4];
    __shared__ float Bs[KT][NT];
    __shared__ float red[16][NT];

    int t = threadIdx.x;
    int tr = t >> 4;
    int tc = t & 15;
    int lr = t >> 2;
    int lk = (t & 3) * 8;
    const float* arow = (lr < rows) ? (H1 + (size_t)(base + m0 + lr) * DH) : nullptr;

    float acc[4][8];
    #pragma unroll
    for (int i = 0; i < 4; i++)
        #pragma unroll
        for (int j = 0; j < 8; j++) acc[i][j] = 0.f;

    const float* Wp = W2 + (size_t)c * DH * DH + n0;

    for (int k0 = 0; k0 < DH; k0 += KT) {
        __syncthreads();
        if (arow) {
            float4 v0 = *(const float4*)(arow + k0 + lk);
            float4 v1 = *(const float4*)(arow + k0 + lk + 4);
            As[lk + 0][lr] = v0.x; As[lk + 1][lr] = v0.y;
            As[lk + 2][lr] = v0.z; As[lk + 3][lr] = v0.w;
            As[lk + 4][lr] = v1.x; As[lk + 5][lr] = v1.y;
            As[lk + 6][lr] = v1.z; As[lk + 7][lr] = v1.w;
        } else {
            #pragma unroll
            for (int i = 0; i < 8; i++) As[lk + i][lr] = 0.f;
        }
        #pragma unroll
        for (int i = 0; i < 4; i++) {
            int idx = i * 256 + t;
            int kk = idx >> 5;
            int cv = idx & 31;
            *(float4*)&Bs[kk][cv * 4] = *(const float4*)(Wp + (size_t)(k0 + kk) * DH + cv * 4);
        }
        __syncthreads();
        #pragma unroll
        for (int k = 0; k < KT; k++) {
            float4 av  = *(const float4*)&As[k][4 * tr];
            float4 bv0 = *(const float4*)&Bs[k][4 * tc];
            float4 bv1 = *(const float4*)&Bs[k][64 + 4 * tc];
            float a[4] = {av.x, av.y, av.z, av.w};
            float b[8] = {bv0.x, bv0.y, bv0.z, bv0.w, bv1.x, bv1.y, bv1.z, bv1.w};
            #pragma unroll
            for (int i = 0; i < 4; i++)
                #pragma unroll
                for (int j = 0; j < 8; j++)
                    acc[i][j] = fmaf(a[i], b[j], acc[i][j]);
        }
    }

    __syncthreads();
    #pragma unroll
    for (int j = 0; j < 8; j++) {
        int cidx = (j < 4) ? (4 * tc + j) : (64 + 4 * tc + (j - 4));
        float bias = b2[c * DH + n0 + cidx];
        float s = 0.f;
        #pragma unroll
        for (int i = 0; i < 4; i++) {
            if (4 * tr + i < rows) s += fmaxf(acc[i][j] + bias, 0.f);
        }
        red[tr][cidx] = s;
    }
    __syncthreads();
    if (t < NT) {
        float s = 0.f;
        #pragma unroll
        for (int r = 0; r < 16; r++) s += red[r][t];
        atomicAdd(&pooled[c * DH + n0 + t], s);
    }
}

// ---------------- launcher ----------------

extern "C" void kernel_launch(void* const* d_in, const int* in_sizes, int n_in,
                              void* d_out, int out_size, void* d_ws, size_t ws_size,
                              hipStream_t stream) {
    (void)n_in; (void)out_size;
    const float* x    = (const float*)d_in[0];
    const int*   cid  = (const int*)d_in[1];
    const float* W1   = (const float*)d_in[2];
    const float* b1   = (const float*)d_in[3];
    const float* W2   = (const float*)d_in[4];
    const float* b2   = (const float*)d_in[5];
    const float* Wfc  = (const float*)d_in[6];
    const float* bfc  = (const float*)d_in[7];
    const float* Wa   = (const float*)d_in[8];
    const float* ba   = (const float*)d_in[9];
    const float* Wb   = (const float*)d_in[10];
    const float* bb   = (const float*)d_in[11];
    const float* Wc   = (const float*)d_in[12];
    const float* bc   = (const float*)d_in[13];
    const float* Wr   = (const float*)d_in[14];
    const float* br   = (const float*)d_in[15];
    const float* Wcls = (const float*)d_in[16];
    const float* bcls = (const float*)d_in[17];
    float* out = (float*)d_out;
    float* ws  = (float*)d_ws;

    int n = in_sizes[1];

    // ---- fast layout ----
    float* pooled   = ws;                          // 5120 f
    int*   scat_pos = (int*)(ws + 5120);           // 16 i (doubles as counts)
    float* a_logit  = ws + 5136;                   // 16 f  (zeroed by memset)
    float* hfc      = ws + 5152;                   // 5120 f -> 10272
    int*   bucket   = (int*)(ws + 10272);          // CNUM * n (padded per-cluster)

    size_t big0 = (((size_t)(10272 + (size_t)CNUM * n) * 4) + 255) & ~(size_t)255;
    size_t w1t_bytes = (size_t)CNUM * DH * DIN * 2;
    size_t w2t_bytes = (size_t)CNUM * DH * DH * 2;
    size_t h1_bytes  = (size_t)(n + 64 * CNUM) * DH * 2;   // compact 64-padded rows
    size_t xb_bytes  = (size_t)n * DIN * 2;
    size_t need = big0 + w1t_bytes + w2t_bytes + h1_bytes + xb_bytes;

    if (ws_size >= need) {
        ushort_t* W1t = (ushort_t*)((char*)d_ws + big0);
        ushort_t* W2t = (ushort_t*)((char*)d_ws + big0 + w1t_bytes);
        ushort_t* H1  = (ushort_t*)((char*)d_ws + big0 + w1t_bytes + w2t_bytes);
        ushort_t* xb  = (ushort_t*)((char*)d_ws + big0 + w1t_bytes + w2t_bytes + h1_bytes);

        int nxb = (n + 3) / 4;
        int nw  = 128 * 2 * CNUM;
        // 64-row m-tiles: sum ceil(cnt/64) <= n/64 + CNUM; round up to mult of 8
        int MAXT = ((n / 64 + CNUM + 1) + 7) & ~7;

        hipMemsetAsync(ws, 0, 5152 * 4, stream);   // pooled + scat_pos + a_logit
        k_prep<<<NSC + nxb + nw, 256, 0, stream>>>(
            cid, n, x, W1, W2, xb, W1t, W2t, nxb, nw, scat_pos, bucket);
        k_g1<<<8 * MAXT, 256, 0, stream>>>(xb, W1t, b1, bucket, scat_pos, n, MAXT, H1);
        k_g2<<<8 * MAXT, 256, 0, stream>>>(H1, W2t, b2, scat_pos, n, MAXT, pooled);
        k_fc2<<<dim3(CNUM, 8), 256, 0, stream>>>(pooled, scat_pos, Wfc, bfc, hfc);
        k_gate2<<<dim3(CNUM, 4), 256, 0, stream>>>(hfc, Wa, ba, Wb, bb, Wc, bc, a_logit);
        k_final<<<1, 1024, 0, stream>>>(hfc, a_logit, Wr, br, Wcls, bcls, out);
    } else {
        // ---- fallback: old fp32 pipeline, old layout ----
        float* pooledF     = ws + 0;
        int*   countsF     = (int*)(ws + 5120);
        int*   offsetsF    = (int*)(ws + 5136);
        float* a_logitF    = ws + 5168;
        int*   scat_posF   = (int*)(ws + 5184);
        float* hfcF        = ws + 5200;
        int*   counts_part = (int*)(ws + 10320);
        int*   bucketF     = (int*)(ws + 11344);

        k_hist<<<NH + 1, 256, 0, stream>>>(cid, n, bc, counts_part, pooledF, a_logitF, scat_posF);
        k_scat_fb<<<NSC, 256, 0, stream>>>(cid, n, counts_part, countsF, offsetsF, scat_posF, bucketF);

        float* H1f = ws + ((11344 + n + 31) & ~31);
        dim3 gg((n + MT - 1) / MT, DH / NT, CNUM);
        k_gemm1<<<gg, 256, 0, stream>>>(x, W1, b1, bucketF, offsetsF, countsF, H1f);
        k_gemm2<<<gg, 256, 0, stream>>>(H1f, W2, b2, offsetsF, countsF, pooledF);

        k_fc2<<<dim3(CNUM, 8), 256, 0, stream>>>(pooledF, countsF, Wfc, bfc, hfcF);
        k_gate2_fb<<<dim3(CNUM, 4), 256, 0, stream>>>(hfcF, Wa, ba, Wb, bb, Wc, a_logitF);
        k_final<<<1, 1024, 0, stream>>>(hfcF, a_logitF, Wr, br, Wcls, bcls, out);
    }
}